// Round 1
// baseline (485.865 us; speedup 1.0000x reference)
//
#include <hip/hip_runtime.h>
#include <hip/hip_bf16.h>
#include <math.h>

// N=100000 nodes, E=600000 edges, F=H=128, B=250 graphs, 400 nodes/graph.
//
// Pipeline (bf16 h, fp32 accum):
//   memset(zero region) -> count+wtrans -> prep (x->bf16, dinv, cluster, pcnts)
//   -> scan_block -> scan_add2 -> fill (CSR (col,w) int2)
//   -> 3x layer_fused: per 64-node block
//        phase1: agg (4 nodes/wave, unroll-4 gathers) -> LDS A-tile
//        phase2: swapped-operand MFMA (Wt read from global, L2-hot)
//        epilogue: layers 1-2 relu+store; layer 3 pooled LDS ds_add + global atomics
//   -> head2
//
// R1-R6: see history (671 -> 337): pool partials, bf16 gathers, MFMA gemm,
//        4-node/wave agg + edge weights, unroll-4 gathers, swapped-operand epilogue.
// R7: fuse agg+gemm per layer (kill ab round-trip, 51MB/layer); fuse pooling into
//     layer-3 epilogue (kill hb write + pool_part); merge small kernels; 1 memset.
//     Dispatches 17 -> 10. Gather phase is BW-bound (4KB in flight/wave), so the
//     fused kernel's possibly-lower occupancy should not slow gathers.

#define WPAD 136   // padded LDS row stride (ushorts) -> 272B rows, 2-way banks (free)

typedef __attribute__((ext_vector_type(8))) short bf16x8;
typedef __attribute__((ext_vector_type(4))) float f32x4;

__device__ __forceinline__ float bflo(unsigned u) { return __uint_as_float(u << 16); }
__device__ __forceinline__ float bfhi(unsigned u) { return __uint_as_float(u & 0xffff0000u); }
__device__ __forceinline__ unsigned short bf16r(float f) {
    unsigned u = __float_as_uint(f);
    return (unsigned short)((u + 0x7fffu + ((u >> 16) & 1u)) >> 16);
}
__device__ __forceinline__ unsigned pack_bf16(float a, float b) {
    return (unsigned)bf16r(a) | ((unsigned)bf16r(b) << 16);
}
__device__ __forceinline__ void fma8(float* acc, float w, uint4 u) {
    acc[0] += w * bflo(u.x); acc[1] += w * bfhi(u.x);
    acc[2] += w * bflo(u.y); acc[3] += w * bfhi(u.y);
    acc[4] += w * bflo(u.z); acc[5] += w * bfhi(u.z);
    acc[6] += w * bflo(u.w); acc[7] += w * bfhi(u.w);
}

// ---------------- CSR build ----------------

// merged: blocks [0,cb) count degrees; blocks [cb,cb+192) transpose W1..W3 to bf16
__global__ void count_wtrans(const int* __restrict__ dst, int* __restrict__ cnt, int ne,
                             const float* __restrict__ W1, const float* __restrict__ W2,
                             const float* __restrict__ W3, unsigned short* __restrict__ Wt,
                             int cb) {
    int b = blockIdx.x;
    if (b < cb) {
        int e = b * 256 + threadIdx.x;
        if (e < ne) atomicAdd(&cnt[dst[e]], 1);
    } else {
        int bb = b - cb;                               // 0..191
        int idx = (bb & 63) * 256 + threadIdx.x;       // 0..16383
        int layer = bb >> 6;
        const float* W = (layer == 0) ? W1 : (layer == 1) ? W2 : W3;
        int n = idx >> 7, k = idx & 127;
        Wt[layer * 16384 + n * 128 + k] = bf16r(W[k * 128 + n]);
    }
}

// fused: x -> bf16, plus per-row dinv, cluster, and (graph,cluster) counts
__global__ void prep_kernel(const float* __restrict__ x, unsigned* __restrict__ hb,
                            const int* __restrict__ cnt, float* __restrict__ dinv,
                            int* __restrict__ cluster, int* __restrict__ pcnts,
                            int npg, int n32) {
    int i = blockIdx.x * blockDim.x + threadIdx.x;   // handles 4 floats
    if (i >= n32) return;
    float4 v = ((const float4*)x)[i];
    hb[i * 2 + 0] = pack_bf16(v.x, v.y);
    hb[i * 2 + 1] = pack_bf16(v.z, v.w);
    if ((i & 31) == 31) {                            // floats 124..127 of this row
        int row = i >> 5;
        dinv[row] = rsqrtf((float)(cnt[row] + 1));
        int c = (int)(v.w + 2.0f * v.z + 0.5f);
        cluster[row] = c;
        atomicAdd(&pcnts[(row / npg) * 3 + c], 1);
    }
}

// exclusive scan of cnt -> row_ptr, 1024 elements per block
__global__ void scan_block(const int* __restrict__ in, int* __restrict__ out,
                           int* __restrict__ bsums, int n) {
    __shared__ int lds[256];
    int t = threadIdx.x;
    int base = blockIdx.x * 1024 + t * 4;
    int v0 = (base + 0 < n) ? in[base + 0] : 0;
    int v1 = (base + 1 < n) ? in[base + 1] : 0;
    int v2 = (base + 2 < n) ? in[base + 2] : 0;
    int v3 = (base + 3 < n) ? in[base + 3] : 0;
    int s = v0 + v1 + v2 + v3;
    lds[t] = s;
    __syncthreads();
    for (int off = 1; off < 256; off <<= 1) {
        int add = (t >= off) ? lds[t - off] : 0;
        __syncthreads();
        lds[t] += add;
        __syncthreads();
    }
    int excl = lds[t] - s;
    if (base + 0 < n) out[base + 0] = excl;
    if (base + 1 < n) out[base + 1] = excl + v0;
    if (base + 2 < n) out[base + 2] = excl + v0 + v1;
    if (base + 3 < n) out[base + 3] = excl + v0 + v1 + v2;
    if (t == 255) bsums[blockIdx.x] = lds[255];
}

// merged scan_bsums+scan_add: each block reduces bsums[0..blockIdx) itself (<=97 adds)
__global__ void scan_add2(int* __restrict__ out, const int* __restrict__ bsums, int n) {
    __shared__ int red[256];
    int t = threadIdx.x;
    red[t] = (t < blockIdx.x) ? bsums[t] : 0;
    __syncthreads();
    for (int off = 128; off > 0; off >>= 1) {
        if (t < off) red[t] += red[t + off];
        __syncthreads();
    }
    int add = red[0];
    int base = blockIdx.x * 1024 + t * 4;
#pragma unroll
    for (int i = 0; i < 4; ++i)
        if (base + i < n) out[base + i] += add;
}

// CSR fill with precomputed edge weight: ce[pos] = (src, dinv[src]*dinv[dst])
__global__ void fill_kernel(const int* __restrict__ src, const int* __restrict__ dst,
                            const int* __restrict__ row_ptr, int* __restrict__ fill,
                            int2* __restrict__ ce, const float* __restrict__ dinv,
                            int ne) {
    int e = blockIdx.x * blockDim.x + threadIdx.x;
    if (e < ne) {
        int d = dst[e], s = src[e];
        int pos = row_ptr[d] + atomicAdd(&fill[d], 1);
        ce[pos] = make_int2(s, __float_as_int(dinv[s] * dinv[d]));
    }
}

// ---------------- fused layer: agg (64 nodes -> LDS) + MFMA gemm + epilogue ------
// MODE 1: hout = relu(A@W + b)   MODE 0: hout = A@W + b
// MODE 2: pooled: per-(graph,cluster) column sums of (A@W + b) via LDS+global atomics

template <int MODE>
__global__ __launch_bounds__(256) void layer_fused(
    const uint4* __restrict__ hin4, unsigned short* __restrict__ hout,
    const int* __restrict__ row_ptr, const int* __restrict__ cnt,
    const int2* __restrict__ ce, const float* __restrict__ dinv,
    const unsigned short* __restrict__ wt, const float* __restrict__ bias,
    const int* __restrict__ cluster, float* __restrict__ gsum,
    int n, int npg, int nb) {
    __shared__ unsigned short smA[64 * WPAD];           // 17408 B aggregated tile
    __shared__ float smP[(MODE == 2) ? 768 : 4];        // pooled partials (MODE 2)

    const int t = threadIdx.x;
    const int wave = t >> 6, lane = t & 63;
    const int quad = lane >> 4, lr = lane & 15;         // quad = node slot / col quad
    const int nbase = blockIdx.x * 64;

    if (MODE == 2) {
        smP[t] = 0.f; smP[t + 256] = 0.f; smP[t + 512] = 0.f;
    }

    // ---- phase 1: aggregate 64 rows into smA (rolled passes to cap VGPR) ----
#pragma unroll 1
    for (int pass = 0; pass < 4; ++pass) {
        int r = pass * 16 + wave * 4 + quad;            // row in block, 0..63
        int node = nbase + r;
        bool ok = node < n;
        int nc = ok ? node : (n - 1);
        float di = dinv[nc];
        uint4 self = hin4[(size_t)nc * 16 + lr];
        float w0 = di * di;
        float acc[8];
        acc[0] = w0 * bflo(self.x); acc[1] = w0 * bfhi(self.x);
        acc[2] = w0 * bflo(self.y); acc[3] = w0 * bfhi(self.y);
        acc[4] = w0 * bflo(self.z); acc[5] = w0 * bfhi(self.z);
        acc[6] = w0 * bflo(self.w); acc[7] = w0 * bfhi(self.w);
        int s0 = row_ptr[nc];
        int deg = ok ? cnt[nc] : 0;
        int2 c0, c1, c2, c3;
        if (deg > 0) {
            int dm = deg - 1;
            c0 = ce[s0];
            c1 = ce[s0 + min(1, dm)];
            c2 = ce[s0 + min(2, dm)];
            c3 = ce[s0 + min(3, dm)];
        }
        for (int i = 0; i < deg; i += 4) {
            int2 p0 = c0, p1 = c1, p2 = c2, p3 = c3;
            int nx = i + 4;
            if (nx < deg) {                             // prefetch next quad
                int dm = deg - 1;
                c0 = ce[s0 + nx];
                c1 = ce[s0 + min(nx + 1, dm)];
                c2 = ce[s0 + min(nx + 2, dm)];
                c3 = ce[s0 + min(nx + 3, dm)];
            }
            uint4 u0 = hin4[(size_t)p0.x * 16 + lr];    // 4 gathers in flight
            uint4 u1 = hin4[(size_t)p1.x * 16 + lr];
            uint4 u2 = hin4[(size_t)p2.x * 16 + lr];
            uint4 u3 = hin4[(size_t)p3.x * 16 + lr];
            float w1 = (i + 1 < deg) ? __int_as_float(p1.y) : 0.f;
            float w2 = (i + 2 < deg) ? __int_as_float(p2.y) : 0.f;
            float w3 = (i + 3 < deg) ? __int_as_float(p3.y) : 0.f;
            fma8(acc, __int_as_float(p0.y), u0);
            fma8(acc, w1, u1);
            fma8(acc, w2, u2);
            fma8(acc, w3, u3);
        }
        uint4 o;
        o.x = pack_bf16(acc[0], acc[1]);
        o.y = pack_bf16(acc[2], acc[3]);
        o.z = pack_bf16(acc[4], acc[5]);
        o.w = pack_bf16(acc[6], acc[7]);
        *(uint4*)(smA + r * WPAD + lr * 8) = o;         // garbage rows fine (finite)
    }
    __syncthreads();

    // ---- phase 2: per-wave 16-row swapped-operand MFMA, Wt direct from global ----
    // mfma(w_frag, a_frag): lane(quad,lr) reg j -> C[row0+lr][ct*16+quad*4+j]
    f32x4 acc2[8];
#pragma unroll
    for (int ct = 0; ct < 8; ++ct) acc2[ct] = (f32x4){0.f, 0.f, 0.f, 0.f};
    const unsigned short* arow = smA + (wave * 16 + lr) * WPAD;
#pragma unroll
    for (int kc = 0; kc < 4; ++kc) {
        int kb = kc * 32 + quad * 8;
        bf16x8 a = *(const bf16x8*)(arow + kb);
#pragma unroll
        for (int ct = 0; ct < 8; ++ct) {
            bf16x8 w = *(const bf16x8*)(wt + (ct * 16 + lr) * 128 + kb);
            acc2[ct] = __builtin_amdgcn_mfma_f32_16x16x32_bf16(w, a, acc2[ct], 0, 0, 0);
        }
    }

    const int row = wave * 16 + lr;
    if (MODE != 2) {
        unsigned short* crow = hout + (size_t)(nbase + row) * 128;
#pragma unroll
        for (int ct = 0; ct < 8; ++ct) {
            float4 bq = *(const float4*)&bias[ct * 16 + quad * 4];
            float v0 = acc2[ct][0] + bq.x;
            float v1 = acc2[ct][1] + bq.y;
            float v2 = acc2[ct][2] + bq.z;
            float v3 = acc2[ct][3] + bq.w;
            if (MODE == 1) {
                v0 = fmaxf(v0, 0.f); v1 = fmaxf(v1, 0.f);
                v2 = fmaxf(v2, 0.f); v3 = fmaxf(v3, 0.f);
            }
            uint2 p;
            p.x = pack_bf16(v0, v1);
            p.y = pack_bf16(v2, v3);
            *(uint2*)(crow + ct * 16 + quad * 4) = p;
        }
    } else {
        int node = nbase + row;
        int g0 = nbase / npg;
        if (node < n) {
            int seg = (node / npg - g0) * 3 + cluster[node];   // 0..5
            float* sp = smP + seg * 128 + quad * 4;
#pragma unroll
            for (int ct = 0; ct < 8; ++ct) {
                float4 bq = *(const float4*)&bias[ct * 16 + quad * 4];
                atomicAdd(&sp[ct * 16 + 0], acc2[ct][0] + bq.x);
                atomicAdd(&sp[ct * 16 + 1], acc2[ct][1] + bq.y);
                atomicAdd(&sp[ct * 16 + 2], acc2[ct][2] + bq.z);
                atomicAdd(&sp[ct * 16 + 3], acc2[ct][3] + bq.w);
            }
        }
        __syncthreads();
#pragma unroll
        for (int s = 0; s < 3; ++s) {
            int idx = t + s * 256;                      // 0..767
            int seg = idx >> 7, col = idx & 127;
            int gidx = g0 + ((seg >= 3) ? 1 : 0);
            int cl = (seg >= 3) ? seg - 3 : seg;
            float v = smP[idx];
            if (v != 0.f && gidx < nb)
                atomicAdd(&gsum[(size_t)(gidx * 3 + cl) * 128 + col], v);
        }
    }
}

// ---------------- head: z = sum_c mean_c . Wl_c, sigmoid ----------------

__global__ void head2(const float* __restrict__ gsum, const int* __restrict__ pcnts,
                      const float* __restrict__ Wl, const float* __restrict__ bl,
                      float* __restrict__ out) {
    int b = blockIdx.x, t = threadIdx.x;    // 128 threads
    float z = 0.f;
#pragma unroll
    for (int c = 0; c < 3; ++c) {
        float s = gsum[(size_t)(b * 3 + c) * 128 + t];
        float n = (float)pcnts[b * 3 + c];
        z += s * (1.0f / fmaxf(n, 1.0f)) * Wl[c * 128 + t];
    }
    for (int off = 32; off > 0; off >>= 1) z += __shfl_down(z, off);
    __shared__ float partial[2];
    if ((t & 63) == 0) partial[t >> 6] = z;
    __syncthreads();
    if (t == 0) {
        float zz = partial[0] + partial[1] + bl[0];
        out[b] = 1.0f / (1.0f + expf(-zz));
    }
}

// ---------------- host ----------------

extern "C" void kernel_launch(void* const* d_in, const int* in_sizes, int n_in,
                              void* d_out, int out_size, void* d_ws, size_t ws_size,
                              hipStream_t stream) {
    const float* x  = (const float*)d_in[0];
    const int*   ei = (const int*)d_in[1];
    const float* W1 = (const float*)d_in[3];
    const float* b1 = (const float*)d_in[4];
    const float* W2 = (const float*)d_in[5];
    const float* b2 = (const float*)d_in[6];
    const float* W3 = (const float*)d_in[7];
    const float* b3 = (const float*)d_in[8];
    const float* Wl = (const float*)d_in[9];
    const float* bl = (const float*)d_in[10];
    float* out = (float*)d_out;

    const int N = in_sizes[0] / 128;        // 100000
    const int E = in_sizes[1] / 2;          // 600000
    const int B = out_size;                 // 250
    const int Npad = (N + 63) & ~63;        // 100032 (64-row blocks)
    const int npg = N / B;                  // 400

    const int* srcp = ei;
    const int* dstp = ei + E;

    char* ws = (char*)d_ws;
    size_t off = 0;
    auto alloc = [&](size_t bytes) -> char* {
        char* p = ws + off;
        off += (bytes + 255) & ~(size_t)255;
        return p;
    };
    unsigned short* hb  = (unsigned short*)alloc((size_t)Npad * 128 * 2); // bf16 h
    unsigned short* ab  = (unsigned short*)alloc((size_t)Npad * 128 * 2); // bf16 pingpong
    unsigned short* wt  = (unsigned short*)alloc((size_t)3 * 16384 * 2);  // Wt bf16 x3
    float* dinv    = (float*)alloc((size_t)N * 4);
    int*   row_ptr = (int*)  alloc((size_t)N * 4);
    int*   cluster = (int*)  alloc((size_t)N * 4);
    int2*  ce      = (int2*) alloc((size_t)E * 8);
    int*   bsums   = (int*)  alloc(512 * 4);
    // --- contiguous zero-region: cnt | fill | pcnts | gsum (one memset) ---
    int*   cnt     = (int*)  alloc((size_t)N * 4);
    int*   fill    = (int*)  alloc((size_t)N * 4);
    int*   pcnts   = (int*)  alloc((size_t)B * 3 * 4);
    float* gsum    = (float*)alloc((size_t)B * 3 * 128 * 4);
    size_t zspan = (size_t)((char*)gsum + (size_t)B * 3 * 128 * 4 - (char*)cnt);
    (void)ws_size; (void)n_in;

    hipMemsetAsync(cnt, 0, zspan, stream);

    int cb = (E + 255) / 256;               // 2344
    count_wtrans<<<cb + 192, 256, 0, stream>>>(dstp, cnt, E, W1, W2, W3, wt, cb);
    prep_kernel<<<(N * 32 + 255) / 256, 256, 0, stream>>>(x, (unsigned*)hb, cnt,
                                                          dinv, cluster, pcnts,
                                                          npg, N * 32);

    int scanBlocks = (N + 1023) / 1024;     // 98
    scan_block<<<scanBlocks, 256, 0, stream>>>(cnt, row_ptr, bsums, N);
    scan_add2<<<scanBlocks, 256, 0, stream>>>(row_ptr, bsums, N);

    fill_kernel<<<(E + 255) / 256, 256, 0, stream>>>(srcp, dstp, row_ptr, fill,
                                                     ce, dinv, E);

    int layerBlocks = Npad / 64;            // 1563
    layer_fused<1><<<layerBlocks, 256, 0, stream>>>(
        (const uint4*)hb, ab, row_ptr, cnt, ce, dinv, wt,         b1,
        cluster, gsum, N, npg, B);
    layer_fused<1><<<layerBlocks, 256, 0, stream>>>(
        (const uint4*)ab, hb, row_ptr, cnt, ce, dinv, wt + 16384, b2,
        cluster, gsum, N, npg, B);
    layer_fused<2><<<layerBlocks, 256, 0, stream>>>(
        (const uint4*)hb, ab, row_ptr, cnt, ce, dinv, wt + 32768, b3,
        cluster, gsum, N, npg, B);

    head2<<<B, 128, 0, stream>>>(gsum, pcnts, Wl, bl, out);
}

// Round 2
// 474.087 us; speedup vs baseline: 1.0248x; 1.0248x over previous
//
#include <hip/hip_runtime.h>
#include <hip/hip_bf16.h>
#include <math.h>

// N=100000 nodes, E=600000 edges, F=H=128, B=250 graphs, 400 nodes/graph.
//
// Pipeline (bf16 h, fp32 accum):
//   memset(zero region) -> count+wtrans -> prep (x->bf16, dinv, cluster, pcnts)
//   -> scan_block -> scan_add2 -> fill (CSR (col,w) int2)
//   -> 3x { agg: ab = (D^-1/2 (A+I) D^-1/2) hb   (4 nodes/wave, unroll-4 gathers)
//           gemm_mfma<MODE>: hb = [relu](ab @ W + b), MODE 2 = pooled epilogue }
//   -> head2
//
// R1-R6: 671 -> 337: pool partials, bf16 gathers, MFMA gemm, 4-node/wave agg +
//        edge weights, unroll-4 in-flight gathers, swapped-operand direct-store.
// R7 FAILED (486): fusing agg+gemm into 64-row blocks collapsed wave count
//     25000->6252 and added block-level degree imbalance at the barrier ->
//     latency-bound (occ 26%, VALU 11%, HBM 7.5%). Gather speed comes from
//     MANY independent waves, not per-wave depth alone. REVERTED.
// R8: separate agg/gemm restored; kept R7's independent wins: pooling fused
//     into layer-3 gemm epilogue (pool_part + layer-3 h round-trip gone),
//     merged count+wtrans, merged scan, pcnts in prep, single memset.
//     17 -> 13 dispatches.

#define WAVE 64
#define WPAD 136   // padded LDS row stride (ushorts) for conflict-free ds_read_b128

typedef __attribute__((ext_vector_type(8))) short bf16x8;
typedef __attribute__((ext_vector_type(4))) float f32x4;

__device__ __forceinline__ float bflo(unsigned u) { return __uint_as_float(u << 16); }
__device__ __forceinline__ float bfhi(unsigned u) { return __uint_as_float(u & 0xffff0000u); }
__device__ __forceinline__ unsigned short bf16r(float f) {
    unsigned u = __float_as_uint(f);
    return (unsigned short)((u + 0x7fffu + ((u >> 16) & 1u)) >> 16);
}
__device__ __forceinline__ unsigned pack_bf16(float a, float b) {
    return (unsigned)bf16r(a) | ((unsigned)bf16r(b) << 16);
}
__device__ __forceinline__ void fma8(float* acc, float w, uint4 u) {
    acc[0] += w * bflo(u.x); acc[1] += w * bfhi(u.x);
    acc[2] += w * bflo(u.y); acc[3] += w * bfhi(u.y);
    acc[4] += w * bflo(u.z); acc[5] += w * bfhi(u.z);
    acc[6] += w * bflo(u.w); acc[7] += w * bfhi(u.w);
}

// ---------------- CSR build ----------------

// merged: blocks [0,cb) count degrees; blocks [cb,cb+192) transpose W1..W3 to bf16
__global__ void count_wtrans(const int* __restrict__ dst, int* __restrict__ cnt, int ne,
                             const float* __restrict__ W1, const float* __restrict__ W2,
                             const float* __restrict__ W3, unsigned short* __restrict__ Wt,
                             int cb) {
    int b = blockIdx.x;
    if (b < cb) {
        int e = b * 256 + threadIdx.x;
        if (e < ne) atomicAdd(&cnt[dst[e]], 1);
    } else {
        int bb = b - cb;                               // 0..191
        int idx = (bb & 63) * 256 + threadIdx.x;       // 0..16383
        int layer = bb >> 6;
        const float* W = (layer == 0) ? W1 : (layer == 1) ? W2 : W3;
        int n = idx >> 7, k = idx & 127;
        Wt[layer * 16384 + n * 128 + k] = bf16r(W[k * 128 + n]);
    }
}

// fused: x -> bf16, plus per-row dinv, cluster, and (graph,cluster) counts
__global__ void prep_kernel(const float* __restrict__ x, unsigned* __restrict__ hb,
                            const int* __restrict__ cnt, float* __restrict__ dinv,
                            int* __restrict__ cluster, int* __restrict__ pcnts,
                            int npg, int n32) {
    int i = blockIdx.x * blockDim.x + threadIdx.x;   // handles 4 floats
    if (i >= n32) return;
    float4 v = ((const float4*)x)[i];
    hb[i * 2 + 0] = pack_bf16(v.x, v.y);
    hb[i * 2 + 1] = pack_bf16(v.z, v.w);
    if ((i & 31) == 31) {                            // floats 124..127 of this row
        int row = i >> 5;
        dinv[row] = rsqrtf((float)(cnt[row] + 1));
        int c = (int)(v.w + 2.0f * v.z + 0.5f);
        cluster[row] = c;
        atomicAdd(&pcnts[(row / npg) * 3 + c], 1);
    }
}

// exclusive scan of cnt -> row_ptr, 1024 elements per block
__global__ void scan_block(const int* __restrict__ in, int* __restrict__ out,
                           int* __restrict__ bsums, int n) {
    __shared__ int lds[256];
    int t = threadIdx.x;
    int base = blockIdx.x * 1024 + t * 4;
    int v0 = (base + 0 < n) ? in[base + 0] : 0;
    int v1 = (base + 1 < n) ? in[base + 1] : 0;
    int v2 = (base + 2 < n) ? in[base + 2] : 0;
    int v3 = (base + 3 < n) ? in[base + 3] : 0;
    int s = v0 + v1 + v2 + v3;
    lds[t] = s;
    __syncthreads();
    for (int off = 1; off < 256; off <<= 1) {
        int add = (t >= off) ? lds[t - off] : 0;
        __syncthreads();
        lds[t] += add;
        __syncthreads();
    }
    int excl = lds[t] - s;
    if (base + 0 < n) out[base + 0] = excl;
    if (base + 1 < n) out[base + 1] = excl + v0;
    if (base + 2 < n) out[base + 2] = excl + v0 + v1;
    if (base + 3 < n) out[base + 3] = excl + v0 + v1 + v2;
    if (t == 255) bsums[blockIdx.x] = lds[255];
}

// merged scan_bsums+scan_add: each block reduces bsums[0..blockIdx) itself (<=97 adds)
__global__ void scan_add2(int* __restrict__ out, const int* __restrict__ bsums, int n) {
    __shared__ int red[256];
    int t = threadIdx.x;
    red[t] = (t < blockIdx.x) ? bsums[t] : 0;
    __syncthreads();
    for (int off = 128; off > 0; off >>= 1) {
        if (t < off) red[t] += red[t + off];
        __syncthreads();
    }
    int add = red[0];
    int base = blockIdx.x * 1024 + t * 4;
#pragma unroll
    for (int i = 0; i < 4; ++i)
        if (base + i < n) out[base + i] += add;
}

// CSR fill with precomputed edge weight: ce[pos] = (src, dinv[src]*dinv[dst])
__global__ void fill_kernel(const int* __restrict__ src, const int* __restrict__ dst,
                            const int* __restrict__ row_ptr, int* __restrict__ fill,
                            int2* __restrict__ ce, const float* __restrict__ dinv,
                            int ne) {
    int e = blockIdx.x * blockDim.x + threadIdx.x;
    if (e < ne) {
        int d = dst[e], s = src[e];
        int pos = row_ptr[d] + atomicAdd(&fill[d], 1);
        ce[pos] = make_int2(s, __float_as_int(dinv[s] * dinv[d]));
    }
}

// ---------------- aggregation: 4 nodes/wave, unroll-4 pipelined gathers ----------
// out[n][:] = dinv[n]^2 * hb[n][:] + sum_{(s,w) in CSR(n)} w * hb[s][:]

__global__ void agg_kernel(const uint4* __restrict__ hb4, uint4* __restrict__ out4,
                           const int* __restrict__ row_ptr, const int* __restrict__ cnt,
                           const int2* __restrict__ ce, const float* __restrict__ dinv,
                           int n) {
    int wid = blockIdx.x * (blockDim.x >> 6) + (threadIdx.x >> 6);
    int lane = threadIdx.x & 63;
    int g = lane >> 4, sl = lane & 15;     // group (node slot) and sublane
    int node = wid * 4 + g;
    bool ok = node < n;
    int nc = ok ? node : (n - 1);
    float di = dinv[nc];
    uint4 self = hb4[(size_t)nc * 16 + sl];
    float w0 = di * di;
    float acc[8];
    acc[0] = w0 * bflo(self.x); acc[1] = w0 * bfhi(self.x);
    acc[2] = w0 * bflo(self.y); acc[3] = w0 * bfhi(self.y);
    acc[4] = w0 * bflo(self.z); acc[5] = w0 * bfhi(self.z);
    acc[6] = w0 * bflo(self.w); acc[7] = w0 * bfhi(self.w);
    int s0 = row_ptr[nc];
    int deg = ok ? cnt[nc] : 0;
    int2 c0, c1, c2, c3;
    if (deg > 0) {
        int dm = deg - 1;
        c0 = ce[s0];
        c1 = ce[s0 + min(1, dm)];
        c2 = ce[s0 + min(2, dm)];
        c3 = ce[s0 + min(3, dm)];
    }
    for (int i = 0; i < deg; i += 4) {
        int2 p0 = c0, p1 = c1, p2 = c2, p3 = c3;
        int nx = i + 4;
        if (nx < deg) {                      // prefetch next quad
            int dm = deg - 1;
            c0 = ce[s0 + nx];
            c1 = ce[s0 + min(nx + 1, dm)];
            c2 = ce[s0 + min(nx + 2, dm)];
            c3 = ce[s0 + min(nx + 3, dm)];
        }
        uint4 u0 = hb4[(size_t)p0.x * 16 + sl];   // 4 gathers in flight
        uint4 u1 = hb4[(size_t)p1.x * 16 + sl];
        uint4 u2 = hb4[(size_t)p2.x * 16 + sl];
        uint4 u3 = hb4[(size_t)p3.x * 16 + sl];
        float w1 = (i + 1 < deg) ? __int_as_float(p1.y) : 0.f;
        float w2 = (i + 2 < deg) ? __int_as_float(p2.y) : 0.f;
        float w3 = (i + 3 < deg) ? __int_as_float(p3.y) : 0.f;
        fma8(acc, __int_as_float(p0.y), u0);
        fma8(acc, w1, u1);
        fma8(acc, w2, u2);
        fma8(acc, w3, u3);
    }
    if (ok) {
        uint4 o;
        o.x = pack_bf16(acc[0], acc[1]);
        o.y = pack_bf16(acc[2], acc[3]);
        o.z = pack_bf16(acc[4], acc[5]);
        o.w = pack_bf16(acc[6], acc[7]);
        out4[(size_t)node * 16 + sl] = o;
    }
}

// ---------------- MFMA bf16 GEMM (swapped operands): Cb = [relu](A @ W + b) --------
// mfma(arg0=Wt-frag, arg1=A-frag): D[i][j] = sum_k Wt[n0+i][k] * A[m0+j][k]
//   = C[m0+j][n0+i].  D layout: lane(quad,lr) reg r -> C[m0+lr][n0+quad*4+r].
// => each lane holds 4 CONSECUTIVE output columns of one row: direct uint2 store.
// Wt staged once per block in LDS (padded); no output LDS, no post-MFMA barriers.
// MODE 1: store relu(.)  MODE 0: store (.)  MODE 2: no store; pooled per-
// (graph,cluster) column sums via LDS atomics + sparse global atomics.

template <int MODE>
__global__ __launch_bounds__(256) void gemm_mfma(const unsigned short* __restrict__ A,
                                                 const unsigned short* __restrict__ Wt,
                                                 const float* __restrict__ bias,
                                                 unsigned short* __restrict__ Cb,
                                                 const int* __restrict__ cluster,
                                                 float* __restrict__ gsum,
                                                 int n, int npg, int nb) {
    __shared__ unsigned short sm[128 * WPAD];   // 34816 B (Wt only)
    __shared__ float smP[(MODE == 2) ? 768 : 4];
    const int t = threadIdx.x;
    const int wave = t >> 6, lane = t & 63;
    const int quad = lane >> 4, lr = lane & 15;
    const size_t row0 = (size_t)blockIdx.x * 128 + wave * 32;

    if (MODE == 2) { smP[t] = 0.f; smP[t + 256] = 0.f; smP[t + 512] = 0.f; }

    {   // stage Wt -> sm (row r = t>>1, half h = t&1)
        int r = t >> 1, h = t & 1;
        const uint4* s = (const uint4*)(Wt + r * 128 + h * 64);
        uint4* d = (uint4*)(sm + r * WPAD + h * 64);
#pragma unroll
        for (int i = 0; i < 8; ++i) d[i] = s[i];
    }
    __syncthreads();

    f32x4 acc[2][8];
#pragma unroll
    for (int i2 = 0; i2 < 2; ++i2)
#pragma unroll
        for (int ct = 0; ct < 8; ++ct) acc[i2][ct] = (f32x4){0.f, 0.f, 0.f, 0.f};

    const unsigned short* arow0 = A + (row0 + lr) * 128;
    const unsigned short* arow1 = arow0 + 16 * 128;
#pragma unroll
    for (int kc = 0; kc < 4; ++kc) {
        int kb = kc * 32 + quad * 8;
        bf16x8 a0 = *(const bf16x8*)(arow0 + kb);   // "B"-operand, m-tile 0
        bf16x8 a1 = *(const bf16x8*)(arow1 + kb);   // m-tile 1
#pragma unroll
        for (int ct = 0; ct < 8; ++ct) {
            bf16x8 w = *(const bf16x8*)(sm + (ct * 16 + lr) * WPAD + kb);
            acc[0][ct] = __builtin_amdgcn_mfma_f32_16x16x32_bf16(w, a0, acc[0][ct], 0, 0, 0);
            acc[1][ct] = __builtin_amdgcn_mfma_f32_16x16x32_bf16(w, a1, acc[1][ct], 0, 0, 0);
        }
    }

    if (MODE != 2) {
        // epilogue: bias + relu, pack 4 bf16 (consecutive cols) -> uint2 direct store
#pragma unroll
        for (int i2 = 0; i2 < 2; ++i2) {
            unsigned short* crow = Cb + (row0 + i2 * 16 + lr) * 128;
#pragma unroll
            for (int ct = 0; ct < 8; ++ct) {
                float4 bq = *(const float4*)&bias[ct * 16 + quad * 4];
                float v0 = acc[i2][ct][0] + bq.x;
                float v1 = acc[i2][ct][1] + bq.y;
                float v2 = acc[i2][ct][2] + bq.z;
                float v3 = acc[i2][ct][3] + bq.w;
                if (MODE == 1) {
                    v0 = fmaxf(v0, 0.f); v1 = fmaxf(v1, 0.f);
                    v2 = fmaxf(v2, 0.f); v3 = fmaxf(v3, 0.f);
                }
                uint2 p;
                p.x = pack_bf16(v0, v1);
                p.y = pack_bf16(v2, v3);
                *(uint2*)(crow + ct * 16 + quad * 4) = p;
            }
        }
    } else {
        // pooled epilogue: 128-row block spans <=2 graphs (128 < npg=400)
        int g0 = (blockIdx.x * 128) / npg;
#pragma unroll
        for (int i2 = 0; i2 < 2; ++i2) {
            int node = (int)row0 + i2 * 16 + lr;
            if (node < n) {
                int seg = (node / npg - g0) * 3 + cluster[node];   // 0..5
                float* sp = smP + seg * 128 + quad * 4;
#pragma unroll
                for (int ct = 0; ct < 8; ++ct) {
                    float4 bq = *(const float4*)&bias[ct * 16 + quad * 4];
                    atomicAdd(&sp[ct * 16 + 0], acc[i2][ct][0] + bq.x);
                    atomicAdd(&sp[ct * 16 + 1], acc[i2][ct][1] + bq.y);
                    atomicAdd(&sp[ct * 16 + 2], acc[i2][ct][2] + bq.z);
                    atomicAdd(&sp[ct * 16 + 3], acc[i2][ct][3] + bq.w);
                }
            }
        }
        __syncthreads();
#pragma unroll
        for (int s = 0; s < 3; ++s) {
            int idx = t + s * 256;                      // 0..767
            int seg = idx >> 7, col = idx & 127;
            int gidx = g0 + ((seg >= 3) ? 1 : 0);
            int cl = (seg >= 3) ? seg - 3 : seg;
            float v = smP[idx];
            if (v != 0.f && gidx < nb)
                atomicAdd(&gsum[(size_t)(gidx * 3 + cl) * 128 + col], v);
        }
    }
}

// ---------------- head: z = sum_c mean_c . Wl_c, sigmoid ----------------

__global__ void head2(const float* __restrict__ gsum, const int* __restrict__ pcnts,
                      const float* __restrict__ Wl, const float* __restrict__ bl,
                      float* __restrict__ out) {
    int b = blockIdx.x, t = threadIdx.x;    // 128 threads
    float z = 0.f;
#pragma unroll
    for (int c = 0; c < 3; ++c) {
        float s = gsum[(size_t)(b * 3 + c) * 128 + t];
        float n = (float)pcnts[b * 3 + c];
        z += s * (1.0f / fmaxf(n, 1.0f)) * Wl[c * 128 + t];
    }
    for (int off = 32; off > 0; off >>= 1) z += __shfl_down(z, off);
    __shared__ float partial[2];
    if ((t & 63) == 0) partial[t >> 6] = z;
    __syncthreads();
    if (t == 0) {
        float zz = partial[0] + partial[1] + bl[0];
        out[b] = 1.0f / (1.0f + expf(-zz));
    }
}

// ---------------- host ----------------

extern "C" void kernel_launch(void* const* d_in, const int* in_sizes, int n_in,
                              void* d_out, int out_size, void* d_ws, size_t ws_size,
                              hipStream_t stream) {
    const float* x  = (const float*)d_in[0];
    const int*   ei = (const int*)d_in[1];
    const float* W1 = (const float*)d_in[3];
    const float* b1 = (const float*)d_in[4];
    const float* W2 = (const float*)d_in[5];
    const float* b2 = (const float*)d_in[6];
    const float* W3 = (const float*)d_in[7];
    const float* b3 = (const float*)d_in[8];
    const float* Wl = (const float*)d_in[9];
    const float* bl = (const float*)d_in[10];
    float* out = (float*)d_out;

    const int N = in_sizes[0] / 128;        // 100000
    const int E = in_sizes[1] / 2;          // 600000
    const int B = out_size;                 // 250
    const int Npad = (N + 127) & ~127;      // 100096
    const int npg = N / B;                  // 400

    const int* srcp = ei;
    const int* dstp = ei + E;

    char* ws = (char*)d_ws;
    size_t off = 0;
    auto alloc = [&](size_t bytes) -> char* {
        char* p = ws + off;
        off += (bytes + 255) & ~(size_t)255;
        return p;
    };
    unsigned short* hb  = (unsigned short*)alloc((size_t)Npad * 128 * 2); // bf16 h
    unsigned short* ab  = (unsigned short*)alloc((size_t)Npad * 128 * 2); // bf16 agg out
    unsigned short* wt  = (unsigned short*)alloc((size_t)3 * 16384 * 2);  // Wt bf16 x3
    float* dinv    = (float*)alloc((size_t)N * 4);
    int*   row_ptr = (int*)  alloc((size_t)N * 4);
    int*   cluster = (int*)  alloc((size_t)N * 4);
    int2*  ce      = (int2*) alloc((size_t)E * 8);
    int*   bsums   = (int*)  alloc(512 * 4);
    // --- contiguous zero-region: cnt | fill | pcnts | gsum (one memset) ---
    int*   cnt     = (int*)  alloc((size_t)N * 4);
    int*   fill    = (int*)  alloc((size_t)N * 4);
    int*   pcnts   = (int*)  alloc((size_t)B * 3 * 4);
    float* gsum    = (float*)alloc((size_t)B * 3 * 128 * 4);
    size_t zspan = (size_t)((char*)gsum + (size_t)B * 3 * 128 * 4 - (char*)cnt);
    (void)ws_size; (void)n_in;

    hipMemsetAsync(cnt, 0, zspan, stream);

    int cb = (E + 255) / 256;               // 2344
    count_wtrans<<<cb + 192, 256, 0, stream>>>(dstp, cnt, E, W1, W2, W3, wt, cb);
    prep_kernel<<<(N * 32 + 255) / 256, 256, 0, stream>>>(x, (unsigned*)hb, cnt,
                                                          dinv, cluster, pcnts,
                                                          npg, N * 32);

    int scanBlocks = (N + 1023) / 1024;     // 98
    scan_block<<<scanBlocks, 256, 0, stream>>>(cnt, row_ptr, bsums, N);
    scan_add2<<<scanBlocks, 256, 0, stream>>>(row_ptr, bsums, N);

    fill_kernel<<<(E + 255) / 256, 256, 0, stream>>>(srcp, dstp, row_ptr, fill,
                                                     ce, dinv, E);

    int gemmBlocks = Npad / 128;            // 782
    int aggBlocks = (N + 15) / 16;          // 6250

    agg_kernel<<<aggBlocks, 256, 0, stream>>>((const uint4*)hb, (uint4*)ab,
                                              row_ptr, cnt, ce, dinv, N);
    gemm_mfma<1><<<gemmBlocks, 256, 0, stream>>>(ab, wt,         b1, hb,
                                                 cluster, gsum, N, npg, B);
    agg_kernel<<<aggBlocks, 256, 0, stream>>>((const uint4*)hb, (uint4*)ab,
                                              row_ptr, cnt, ce, dinv, N);
    gemm_mfma<1><<<gemmBlocks, 256, 0, stream>>>(ab, wt + 16384, b2, hb,
                                                 cluster, gsum, N, npg, B);
    agg_kernel<<<aggBlocks, 256, 0, stream>>>((const uint4*)hb, (uint4*)ab,
                                              row_ptr, cnt, ce, dinv, N);
    gemm_mfma<2><<<gemmBlocks, 256, 0, stream>>>(ab, wt + 32768, b3, hb,
                                                 cluster, gsum, N, npg, B);

    head2<<<B, 128, 0, stream>>>(gsum, pcnts, Wl, bl, out);
}

// Round 3
// 334.310 us; speedup vs baseline: 1.4533x; 1.4181x over previous
//
#include <hip/hip_runtime.h>
#include <hip/hip_bf16.h>
#include <math.h>

// N=100000 nodes, E=600000 edges, F=H=128, B=250 graphs, 400 nodes/graph.
//
// Pipeline (bf16 h, fp32 accum):
//   memset(cnt|fill) -> count+wtrans -> prep (x->bf16 + dinv + cluster)
//   -> scan_block -> scan_add2 -> fill (CSR (col,w) int2)
//   -> 3x { agg: ab = (D^-1/2 (A+I) D^-1/2) hb   (4 nodes/wave, unroll-4 gathers)
//           gemm_mfma: hb = [relu](ab @ W + b)   (swapped-operand, direct stores) }
//   -> pool_part (16 partials/graph) -> head
//
// R1-R6: 671 -> 337: pool partials, bf16 gathers, MFMA gemm, 4-node/wave agg +
//        edge weights, unroll-4 in-flight gathers, swapped-operand direct-store.
// R7 FAILED (486): agg+gemm fusion collapsed wave count + barrier imbalance ->
//        latency-bound (occ 26%). Gather speed = MANY independent waves.
// R8 FAILED (474): pooled MODE-2 gemm epilogue = 102us (LDS atomicAdd with
//        16-way same-address serialization, MfmaUtil 1.2%); prep's pcnts
//        global atomics hammer 12 lines. Fused pooling keeps losing to
//        serialization; the contention-free pool_part partials are cheaper.
// R9: R6 structure restored exactly (plain gemm stores, pool_part + head);
//        kept only the neutral merges: count+wtrans, scan_add2, one memset.
//        12 dispatches.

#define WAVE 64
#define NPARTS 16
#define WPAD 136   // padded LDS row stride (ushorts) for conflict-free ds_read_b128

typedef __attribute__((ext_vector_type(8))) short bf16x8;
typedef __attribute__((ext_vector_type(4))) float f32x4;

__device__ __forceinline__ float bflo(unsigned u) { return __uint_as_float(u << 16); }
__device__ __forceinline__ float bfhi(unsigned u) { return __uint_as_float(u & 0xffff0000u); }
__device__ __forceinline__ float bfs(unsigned short s) {
    return __uint_as_float(((unsigned)s) << 16);
}
__device__ __forceinline__ unsigned short bf16r(float f) {
    unsigned u = __float_as_uint(f);
    return (unsigned short)((u + 0x7fffu + ((u >> 16) & 1u)) >> 16);
}
__device__ __forceinline__ unsigned pack_bf16(float a, float b) {
    return (unsigned)bf16r(a) | ((unsigned)bf16r(b) << 16);
}
__device__ __forceinline__ void fma8(float* acc, float w, uint4 u) {
    acc[0] += w * bflo(u.x); acc[1] += w * bfhi(u.x);
    acc[2] += w * bflo(u.y); acc[3] += w * bfhi(u.y);
    acc[4] += w * bflo(u.z); acc[5] += w * bfhi(u.z);
    acc[6] += w * bflo(u.w); acc[7] += w * bfhi(u.w);
}

// ---------------- CSR build ----------------

// merged: blocks [0,cb) count degrees; blocks [cb,cb+192) transpose W1..W3 to bf16
__global__ void count_wtrans(const int* __restrict__ dst, int* __restrict__ cnt, int ne,
                             const float* __restrict__ W1, const float* __restrict__ W2,
                             const float* __restrict__ W3, unsigned short* __restrict__ Wt,
                             int cb) {
    int b = blockIdx.x;
    if (b < cb) {
        int e = b * 256 + threadIdx.x;
        if (e < ne) atomicAdd(&cnt[dst[e]], 1);
    } else {
        int bb = b - cb;                               // 0..191
        int idx = (bb & 63) * 256 + threadIdx.x;       // 0..16383
        int layer = bb >> 6;
        const float* W = (layer == 0) ? W1 : (layer == 1) ? W2 : W3;
        int n = idx >> 7, k = idx & 127;
        Wt[layer * 16384 + n * 128 + k] = bf16r(W[k * 128 + n]);
    }
}

// fused: x -> bf16, plus per-row dinv and cluster (one pass over x)
__global__ void prep_kernel(const float* __restrict__ x, unsigned* __restrict__ hb,
                            const int* __restrict__ cnt, float* __restrict__ dinv,
                            int* __restrict__ cluster, int n32) {
    int i = blockIdx.x * blockDim.x + threadIdx.x;   // handles 4 floats
    if (i >= n32) return;
    float4 v = ((const float4*)x)[i];
    hb[i * 2 + 0] = pack_bf16(v.x, v.y);
    hb[i * 2 + 1] = pack_bf16(v.z, v.w);
    if ((i & 31) == 31) {                            // floats 124..127 of this row
        int row = i >> 5;
        dinv[row] = rsqrtf((float)(cnt[row] + 1));
        cluster[row] = (int)(v.w + 2.0f * v.z + 0.5f);
    }
}

// exclusive scan of cnt -> row_ptr, 1024 elements per block
__global__ void scan_block(const int* __restrict__ in, int* __restrict__ out,
                           int* __restrict__ bsums, int n) {
    __shared__ int lds[256];
    int t = threadIdx.x;
    int base = blockIdx.x * 1024 + t * 4;
    int v0 = (base + 0 < n) ? in[base + 0] : 0;
    int v1 = (base + 1 < n) ? in[base + 1] : 0;
    int v2 = (base + 2 < n) ? in[base + 2] : 0;
    int v3 = (base + 3 < n) ? in[base + 3] : 0;
    int s = v0 + v1 + v2 + v3;
    lds[t] = s;
    __syncthreads();
    for (int off = 1; off < 256; off <<= 1) {
        int add = (t >= off) ? lds[t - off] : 0;
        __syncthreads();
        lds[t] += add;
        __syncthreads();
    }
    int excl = lds[t] - s;
    if (base + 0 < n) out[base + 0] = excl;
    if (base + 1 < n) out[base + 1] = excl + v0;
    if (base + 2 < n) out[base + 2] = excl + v0 + v1;
    if (base + 3 < n) out[base + 3] = excl + v0 + v1 + v2;
    if (t == 255) bsums[blockIdx.x] = lds[255];
}

// merged scan_bsums+scan_add: each block reduces bsums[0..blockIdx) itself (<=97 adds)
__global__ void scan_add2(int* __restrict__ out, const int* __restrict__ bsums, int n) {
    __shared__ int red[256];
    int t = threadIdx.x;
    red[t] = (t < blockIdx.x) ? bsums[t] : 0;
    __syncthreads();
    for (int off = 128; off > 0; off >>= 1) {
        if (t < off) red[t] += red[t + off];
        __syncthreads();
    }
    int add = red[0];
    int base = blockIdx.x * 1024 + t * 4;
#pragma unroll
    for (int i = 0; i < 4; ++i)
        if (base + i < n) out[base + i] += add;
}

// CSR fill with precomputed edge weight: ce[pos] = (src, dinv[src]*dinv[dst])
__global__ void fill_kernel(const int* __restrict__ src, const int* __restrict__ dst,
                            const int* __restrict__ row_ptr, int* __restrict__ fill,
                            int2* __restrict__ ce, const float* __restrict__ dinv,
                            int ne) {
    int e = blockIdx.x * blockDim.x + threadIdx.x;
    if (e < ne) {
        int d = dst[e], s = src[e];
        int pos = row_ptr[d] + atomicAdd(&fill[d], 1);
        ce[pos] = make_int2(s, __float_as_int(dinv[s] * dinv[d]));
    }
}

// ---------------- aggregation: 4 nodes/wave, unroll-4 pipelined gathers ----------
// out[n][:] = dinv[n]^2 * hb[n][:] + sum_{(s,w) in CSR(n)} w * hb[s][:]

__global__ void agg_kernel(const uint4* __restrict__ hb4, uint4* __restrict__ out4,
                           const int* __restrict__ row_ptr, const int* __restrict__ cnt,
                           const int2* __restrict__ ce, const float* __restrict__ dinv,
                           int n) {
    int wid = blockIdx.x * (blockDim.x >> 6) + (threadIdx.x >> 6);
    int lane = threadIdx.x & 63;
    int g = lane >> 4, sl = lane & 15;     // group (node slot) and sublane
    int node = wid * 4 + g;
    bool ok = node < n;
    int nc = ok ? node : (n - 1);
    float di = dinv[nc];
    uint4 self = hb4[(size_t)nc * 16 + sl];
    float w0 = di * di;
    float acc[8];
    acc[0] = w0 * bflo(self.x); acc[1] = w0 * bfhi(self.x);
    acc[2] = w0 * bflo(self.y); acc[3] = w0 * bfhi(self.y);
    acc[4] = w0 * bflo(self.z); acc[5] = w0 * bfhi(self.z);
    acc[6] = w0 * bflo(self.w); acc[7] = w0 * bfhi(self.w);
    int s0 = row_ptr[nc];
    int deg = ok ? cnt[nc] : 0;
    int2 c0, c1, c2, c3;
    if (deg > 0) {
        int dm = deg - 1;
        c0 = ce[s0];
        c1 = ce[s0 + min(1, dm)];
        c2 = ce[s0 + min(2, dm)];
        c3 = ce[s0 + min(3, dm)];
    }
    for (int i = 0; i < deg; i += 4) {
        int2 p0 = c0, p1 = c1, p2 = c2, p3 = c3;
        int nx = i + 4;
        if (nx < deg) {                      // prefetch next quad
            int dm = deg - 1;
            c0 = ce[s0 + nx];
            c1 = ce[s0 + min(nx + 1, dm)];
            c2 = ce[s0 + min(nx + 2, dm)];
            c3 = ce[s0 + min(nx + 3, dm)];
        }
        uint4 u0 = hb4[(size_t)p0.x * 16 + sl];   // 4 gathers in flight
        uint4 u1 = hb4[(size_t)p1.x * 16 + sl];
        uint4 u2 = hb4[(size_t)p2.x * 16 + sl];
        uint4 u3 = hb4[(size_t)p3.x * 16 + sl];
        float w1 = (i + 1 < deg) ? __int_as_float(p1.y) : 0.f;
        float w2 = (i + 2 < deg) ? __int_as_float(p2.y) : 0.f;
        float w3 = (i + 3 < deg) ? __int_as_float(p3.y) : 0.f;
        fma8(acc, __int_as_float(p0.y), u0);
        fma8(acc, w1, u1);
        fma8(acc, w2, u2);
        fma8(acc, w3, u3);
    }
    if (ok) {
        uint4 o;
        o.x = pack_bf16(acc[0], acc[1]);
        o.y = pack_bf16(acc[2], acc[3]);
        o.z = pack_bf16(acc[4], acc[5]);
        o.w = pack_bf16(acc[6], acc[7]);
        out4[(size_t)node * 16 + sl] = o;
    }
}

// ---------------- MFMA bf16 GEMM (swapped operands): Cb = [relu](A @ W + b) --------
// mfma(arg0=Wt-frag, arg1=A-frag): D[i][j] = sum_k Wt[n0+i][k] * A[m0+j][k]
//   = C[m0+j][n0+i].  D layout: lane(quad,lr) reg r -> C[m0+lr][n0+quad*4+r].
// => each lane holds 4 CONSECUTIVE output columns of one row: direct uint2 store.
// Wt staged once per block in LDS (padded); no output LDS, no post-MFMA barriers.

__global__ __launch_bounds__(256) void gemm_mfma(const unsigned short* __restrict__ A,
                                                 const unsigned short* __restrict__ Wt,
                                                 const float* __restrict__ bias,
                                                 unsigned short* __restrict__ Cb,
                                                 int relu) {
    __shared__ unsigned short sm[128 * WPAD];   // 34816 B (Wt only)
    const int t = threadIdx.x;
    const int wave = t >> 6, lane = t & 63;
    const int quad = lane >> 4, lr = lane & 15;
    const size_t row0 = (size_t)blockIdx.x * 128 + wave * 32;

    {   // stage Wt -> sm (row r = t>>1, half h = t&1)
        int r = t >> 1, h = t & 1;
        const uint4* s = (const uint4*)(Wt + r * 128 + h * 64);
        uint4* d = (uint4*)(sm + r * WPAD + h * 64);
#pragma unroll
        for (int i = 0; i < 8; ++i) d[i] = s[i];
    }
    __syncthreads();

    f32x4 acc[2][8];
#pragma unroll
    for (int i2 = 0; i2 < 2; ++i2)
#pragma unroll
        for (int ct = 0; ct < 8; ++ct) acc[i2][ct] = (f32x4){0.f, 0.f, 0.f, 0.f};

    const unsigned short* arow0 = A + (row0 + lr) * 128;
    const unsigned short* arow1 = arow0 + 16 * 128;
#pragma unroll
    for (int kc = 0; kc < 4; ++kc) {
        int kb = kc * 32 + quad * 8;
        bf16x8 a0 = *(const bf16x8*)(arow0 + kb);   // "B"-operand, m-tile 0
        bf16x8 a1 = *(const bf16x8*)(arow1 + kb);   // m-tile 1
#pragma unroll
        for (int ct = 0; ct < 8; ++ct) {
            bf16x8 w = *(const bf16x8*)(sm + (ct * 16 + lr) * WPAD + kb);
            acc[0][ct] = __builtin_amdgcn_mfma_f32_16x16x32_bf16(w, a0, acc[0][ct], 0, 0, 0);
            acc[1][ct] = __builtin_amdgcn_mfma_f32_16x16x32_bf16(w, a1, acc[1][ct], 0, 0, 0);
        }
    }

    // epilogue: bias + relu, pack 4 bf16 (consecutive cols) -> uint2 direct store
#pragma unroll
    for (int i2 = 0; i2 < 2; ++i2) {
        unsigned short* crow = Cb + (row0 + i2 * 16 + lr) * 128;
#pragma unroll
        for (int ct = 0; ct < 8; ++ct) {
            float4 bq = *(const float4*)&bias[ct * 16 + quad * 4];
            float v0 = acc[i2][ct][0] + bq.x;
            float v1 = acc[i2][ct][1] + bq.y;
            float v2 = acc[i2][ct][2] + bq.z;
            float v3 = acc[i2][ct][3] + bq.w;
            if (relu) {
                v0 = fmaxf(v0, 0.f); v1 = fmaxf(v1, 0.f);
                v2 = fmaxf(v2, 0.f); v3 = fmaxf(v3, 0.f);
            }
            uint2 p;
            p.x = pack_bf16(v0, v1);
            p.y = pack_bf16(v2, v3);
            *(uint2*)(crow + ct * 16 + quad * 4) = p;
        }
    }
}

// ---------------- pooling: 16 partial blocks per graph, bf16 reads ----------------

__global__ void pool_part(const unsigned short* __restrict__ h,
                          const int* __restrict__ cluster,
                          float* __restrict__ part_sums, int* __restrict__ part_cnts,
                          int npg) {
    int blk = blockIdx.x;
    int g = blk / NPARTS, p = blk % NPARTS;
    int j = threadIdx.x;
    int per = npg / NPARTS;
    int base = g * npg + p * per;
    float a0 = 0.f, a1 = 0.f, a2 = 0.f;
    int n0 = 0, n1 = 0, n2 = 0;
    for (int i = 0; i < per; ++i) {
        int node = base + i;
        float v = bfs(h[(size_t)node * 128 + j]);
        int c = cluster[node];
        if (c == 0)      { a0 += v; n0++; }
        else if (c == 1) { a1 += v; n1++; }
        else             { a2 += v; n2++; }
    }
    size_t o = (size_t)blk * 3 * 128 + j;
    part_sums[o]       = a0;
    part_sums[o + 128] = a1;
    part_sums[o + 256] = a2;
    if (j == 0) {
        part_cnts[blk * 3 + 0] = n0;
        part_cnts[blk * 3 + 1] = n1;
        part_cnts[blk * 3 + 2] = n2;
    }
}

__global__ void head_kernel(const float* __restrict__ part_sums,
                            const int* __restrict__ part_cnts,
                            const float* __restrict__ Wl, const float* __restrict__ bl,
                            float* __restrict__ out) {
    int b = blockIdx.x, t = threadIdx.x;
    float s0 = 0.f, s1 = 0.f, s2 = 0.f;
    int n0 = 0, n1 = 0, n2 = 0;
#pragma unroll
    for (int p = 0; p < NPARTS; ++p) {
        int blk = b * NPARTS + p;
        size_t o = (size_t)blk * 3 * 128 + t;
        s0 += part_sums[o];
        s1 += part_sums[o + 128];
        s2 += part_sums[o + 256];
        n0 += part_cnts[blk * 3 + 0];
        n1 += part_cnts[blk * 3 + 1];
        n2 += part_cnts[blk * 3 + 2];
    }
    float z = s0 * (1.0f / fmaxf((float)n0, 1.0f)) * Wl[t]
            + s1 * (1.0f / fmaxf((float)n1, 1.0f)) * Wl[128 + t]
            + s2 * (1.0f / fmaxf((float)n2, 1.0f)) * Wl[256 + t];
    for (int off = 32; off > 0; off >>= 1) z += __shfl_down(z, off);
    __shared__ float partial[2];
    if ((t & 63) == 0) partial[t >> 6] = z;
    __syncthreads();
    if (t == 0) {
        float zz = partial[0] + partial[1] + bl[0];
        out[b] = 1.0f / (1.0f + expf(-zz));
    }
}

// ---------------- host ----------------

extern "C" void kernel_launch(void* const* d_in, const int* in_sizes, int n_in,
                              void* d_out, int out_size, void* d_ws, size_t ws_size,
                              hipStream_t stream) {
    const float* x  = (const float*)d_in[0];
    const int*   ei = (const int*)d_in[1];
    const float* W1 = (const float*)d_in[3];
    const float* b1 = (const float*)d_in[4];
    const float* W2 = (const float*)d_in[5];
    const float* b2 = (const float*)d_in[6];
    const float* W3 = (const float*)d_in[7];
    const float* b3 = (const float*)d_in[8];
    const float* Wl = (const float*)d_in[9];
    const float* bl = (const float*)d_in[10];
    float* out = (float*)d_out;

    const int N = in_sizes[0] / 128;        // 100000
    const int E = in_sizes[1] / 2;          // 600000
    const int B = out_size;                 // 250
    const int Npad = (N + 127) & ~127;      // 100096
    const int npg = N / B;                  // 400

    const int* srcp = ei;
    const int* dstp = ei + E;

    char* ws = (char*)d_ws;
    size_t off = 0;
    auto alloc = [&](size_t bytes) -> char* {
        char* p = ws + off;
        off += (bytes + 255) & ~(size_t)255;
        return p;
    };
    unsigned short* hb  = (unsigned short*)alloc((size_t)Npad * 128 * 2); // bf16 h
    unsigned short* ab  = (unsigned short*)alloc((size_t)Npad * 128 * 2); // bf16 agg out
    unsigned short* wt  = (unsigned short*)alloc((size_t)3 * 16384 * 2);  // Wt bf16 x3
    float* dinv    = (float*)alloc((size_t)N * 4);
    int*   row_ptr = (int*)  alloc((size_t)N * 4);
    int*   cluster = (int*)  alloc((size_t)N * 4);
    int2*  ce      = (int2*) alloc((size_t)E * 8);
    int*   bsums   = (int*)  alloc(512 * 4);
    float* psums   = (float*)alloc((size_t)B * NPARTS * 3 * 128 * 4);
    int*   pcnts   = (int*)  alloc((size_t)B * NPARTS * 3 * 4);
    // --- contiguous zero-region: cnt | fill (one memset) ---
    int*   cnt     = (int*)  alloc((size_t)N * 4);
    int*   fill    = (int*)  alloc((size_t)N * 4);
    size_t zspan = (size_t)((char*)fill + (size_t)N * 4 - (char*)cnt);
    (void)ws_size; (void)n_in;

    hipMemsetAsync(cnt, 0, zspan, stream);

    int cb = (E + 255) / 256;               // 2344
    count_wtrans<<<cb + 192, 256, 0, stream>>>(dstp, cnt, E, W1, W2, W3, wt, cb);
    prep_kernel<<<(N * 32 + 255) / 256, 256, 0, stream>>>(x, (unsigned*)hb, cnt,
                                                          dinv, cluster, N * 32);

    int scanBlocks = (N + 1023) / 1024;     // 98
    scan_block<<<scanBlocks, 256, 0, stream>>>(cnt, row_ptr, bsums, N);
    scan_add2<<<scanBlocks, 256, 0, stream>>>(row_ptr, bsums, N);

    fill_kernel<<<(E + 255) / 256, 256, 0, stream>>>(srcp, dstp, row_ptr, fill,
                                                     ce, dinv, E);

    int gemmBlocks = Npad / 128;            // 782
    int aggBlocks = (N + 15) / 16;          // 6250

    agg_kernel<<<aggBlocks, 256, 0, stream>>>((const uint4*)hb, (uint4*)ab,
                                              row_ptr, cnt, ce, dinv, N);
    gemm_mfma<<<gemmBlocks, 256, 0, stream>>>(ab, wt,         b1, hb, 1);
    agg_kernel<<<aggBlocks, 256, 0, stream>>>((const uint4*)hb, (uint4*)ab,
                                              row_ptr, cnt, ce, dinv, N);
    gemm_mfma<<<gemmBlocks, 256, 0, stream>>>(ab, wt + 16384, b2, hb, 1);
    agg_kernel<<<aggBlocks, 256, 0, stream>>>((const uint4*)hb, (uint4*)ab,
                                              row_ptr, cnt, ce, dinv, N);
    gemm_mfma<<<gemmBlocks, 256, 0, stream>>>(ab, wt + 32768, b3, hb, 0);

    pool_part<<<B * NPARTS, 128, 0, stream>>>(hb, cluster, psums, pcnts, npg);
    head_kernel<<<B, 128, 0, stream>>>(psums, pcnts, Wl, bl, out);
}

// Round 4
// 323.634 us; speedup vs baseline: 1.5013x; 1.0330x over previous
//
#include <hip/hip_runtime.h>
#include <hip/hip_bf16.h>
#include <math.h>

// N=100000 nodes, E=600000 edges, F=H=128, B=250 graphs, 400 nodes/graph.
//
// Pipeline (bf16 h, fp32 accum):
//   memset(cnt|fill) -> count+wtrans+wv -> prep (x->bf16 + dinv + cluster)
//   -> scan_block -> scan_add2 -> fill (CSR (col,w) int2)
//   -> 2x { agg; gemm_mfma relu }  -> agg3 -> pool_part(ab) -> head(wv)
//
// R1-R6: 671 -> 337: pool partials, bf16 gathers, MFMA gemm, 4-node/wave agg +
//        edge weights, unroll-4 in-flight gathers, swapped-operand direct-store.
// R7 FAILED (486): agg+gemm fusion collapsed wave count + barrier imbalance ->
//        latency-bound (occ 26%). Gather speed = MANY independent waves.
// R8 FAILED (474): pooled gemm epilogue = 102us LDS-atomic serialization.
// R9  (334): R6 structure restored + neutral merges (count+wtrans, scan_add2,
//        one memset). 12 dispatches, all <40us.
// R10: layer-3 GEMM eliminated algebraically: pooling commutes with @W3, so
//        z = sum_c (pool_c(ab3)/n_c) . (W3@Wl_c) + [n_c>0] b3.Wl_c + bl.
//        wv = W3@Wl precomputed in 2 extra blocks of count_wtrans; pool reads
//        ab (agg3 out). Kills ~27us GEMM + 25.6MB write + 1 dispatch; one
//        FEWER bf16 rounding than before (C3 never materialized).

#define WAVE 64
#define NPARTS 16
#define WPAD 136   // padded LDS row stride (ushorts) for conflict-free ds_read_b128

typedef __attribute__((ext_vector_type(8))) short bf16x8;
typedef __attribute__((ext_vector_type(4))) float f32x4;

__device__ __forceinline__ float bflo(unsigned u) { return __uint_as_float(u << 16); }
__device__ __forceinline__ float bfhi(unsigned u) { return __uint_as_float(u & 0xffff0000u); }
__device__ __forceinline__ float bfs(unsigned short s) {
    return __uint_as_float(((unsigned)s) << 16);
}
__device__ __forceinline__ unsigned short bf16r(float f) {
    unsigned u = __float_as_uint(f);
    return (unsigned short)((u + 0x7fffu + ((u >> 16) & 1u)) >> 16);
}
__device__ __forceinline__ unsigned pack_bf16(float a, float b) {
    return (unsigned)bf16r(a) | ((unsigned)bf16r(b) << 16);
}
__device__ __forceinline__ void fma8(float* acc, float w, uint4 u) {
    acc[0] += w * bflo(u.x); acc[1] += w * bfhi(u.x);
    acc[2] += w * bflo(u.y); acc[3] += w * bfhi(u.y);
    acc[4] += w * bflo(u.z); acc[5] += w * bfhi(u.z);
    acc[6] += w * bflo(u.w); acc[7] += w * bfhi(u.w);
}

// ---------------- CSR build + weight prep ----------------

// blocks [0,cb): count degrees; [cb,cb+128): transpose W1,W2 to bf16;
// [cb+128,cb+130): wv[c][k] = sum_n W3[k][n] * Wl[c*128+n]  (fp32)
__global__ void count_wtrans(const int* __restrict__ dst, int* __restrict__ cnt, int ne,
                             const float* __restrict__ W1, const float* __restrict__ W2,
                             const float* __restrict__ W3, const float* __restrict__ Wl,
                             unsigned short* __restrict__ Wt, float* __restrict__ wv,
                             int cb) {
    int b = blockIdx.x;
    if (b < cb) {
        int e = b * 256 + threadIdx.x;
        if (e < ne) atomicAdd(&cnt[dst[e]], 1);
    } else if (b < cb + 128) {
        int bb = b - cb;                               // 0..127
        int idx = (bb & 63) * 256 + threadIdx.x;       // 0..16383
        int layer = bb >> 6;                           // 0,1
        const float* W = (layer == 0) ? W1 : W2;
        int n = idx >> 7, k = idx & 127;
        Wt[layer * 16384 + n * 128 + k] = bf16r(W[k * 128 + n]);
    } else {
        int idx = (b - cb - 128) * 256 + threadIdx.x;  // 0..511
        if (idx < 384) {
            int c = idx >> 7, k = idx & 127;
            const float* wlc = Wl + c * 128;
            const float* w3r = W3 + k * 128;
            float s = 0.f;
#pragma unroll 8
            for (int n = 0; n < 128; ++n) s += w3r[n] * wlc[n];
            wv[c * 128 + k] = s;
        }
    }
}

// fused: x -> bf16, plus per-row dinv and cluster (one pass over x)
__global__ void prep_kernel(const float* __restrict__ x, unsigned* __restrict__ hb,
                            const int* __restrict__ cnt, float* __restrict__ dinv,
                            int* __restrict__ cluster, int n32) {
    int i = blockIdx.x * blockDim.x + threadIdx.x;   // handles 4 floats
    if (i >= n32) return;
    float4 v = ((const float4*)x)[i];
    hb[i * 2 + 0] = pack_bf16(v.x, v.y);
    hb[i * 2 + 1] = pack_bf16(v.z, v.w);
    if ((i & 31) == 31) {                            // floats 124..127 of this row
        int row = i >> 5;
        dinv[row] = rsqrtf((float)(cnt[row] + 1));
        cluster[row] = (int)(v.w + 2.0f * v.z + 0.5f);
    }
}

// exclusive scan of cnt -> row_ptr, 1024 elements per block
__global__ void scan_block(const int* __restrict__ in, int* __restrict__ out,
                           int* __restrict__ bsums, int n) {
    __shared__ int lds[256];
    int t = threadIdx.x;
    int base = blockIdx.x * 1024 + t * 4;
    int v0 = (base + 0 < n) ? in[base + 0] : 0;
    int v1 = (base + 1 < n) ? in[base + 1] : 0;
    int v2 = (base + 2 < n) ? in[base + 2] : 0;
    int v3 = (base + 3 < n) ? in[base + 3] : 0;
    int s = v0 + v1 + v2 + v3;
    lds[t] = s;
    __syncthreads();
    for (int off = 1; off < 256; off <<= 1) {
        int add = (t >= off) ? lds[t - off] : 0;
        __syncthreads();
        lds[t] += add;
        __syncthreads();
    }
    int excl = lds[t] - s;
    if (base + 0 < n) out[base + 0] = excl;
    if (base + 1 < n) out[base + 1] = excl + v0;
    if (base + 2 < n) out[base + 2] = excl + v0 + v1;
    if (base + 3 < n) out[base + 3] = excl + v0 + v1 + v2;
    if (t == 255) bsums[blockIdx.x] = lds[255];
}

// merged scan_bsums+scan_add: each block reduces bsums[0..blockIdx) itself (<=97 adds)
__global__ void scan_add2(int* __restrict__ out, const int* __restrict__ bsums, int n) {
    __shared__ int red[256];
    int t = threadIdx.x;
    red[t] = (t < blockIdx.x) ? bsums[t] : 0;
    __syncthreads();
    for (int off = 128; off > 0; off >>= 1) {
        if (t < off) red[t] += red[t + off];
        __syncthreads();
    }
    int add = red[0];
    int base = blockIdx.x * 1024 + t * 4;
#pragma unroll
    for (int i = 0; i < 4; ++i)
        if (base + i < n) out[base + i] += add;
}

// CSR fill with precomputed edge weight: ce[pos] = (src, dinv[src]*dinv[dst])
__global__ void fill_kernel(const int* __restrict__ src, const int* __restrict__ dst,
                            const int* __restrict__ row_ptr, int* __restrict__ fill,
                            int2* __restrict__ ce, const float* __restrict__ dinv,
                            int ne) {
    int e = blockIdx.x * blockDim.x + threadIdx.x;
    if (e < ne) {
        int d = dst[e], s = src[e];
        int pos = row_ptr[d] + atomicAdd(&fill[d], 1);
        ce[pos] = make_int2(s, __float_as_int(dinv[s] * dinv[d]));
    }
}

// ---------------- aggregation: 4 nodes/wave, unroll-4 pipelined gathers ----------
// out[n][:] = dinv[n]^2 * hb[n][:] + sum_{(s,w) in CSR(n)} w * hb[s][:]

__global__ void agg_kernel(const uint4* __restrict__ hb4, uint4* __restrict__ out4,
                           const int* __restrict__ row_ptr, const int* __restrict__ cnt,
                           const int2* __restrict__ ce, const float* __restrict__ dinv,
                           int n) {
    int wid = blockIdx.x * (blockDim.x >> 6) + (threadIdx.x >> 6);
    int lane = threadIdx.x & 63;
    int g = lane >> 4, sl = lane & 15;     // group (node slot) and sublane
    int node = wid * 4 + g;
    bool ok = node < n;
    int nc = ok ? node : (n - 1);
    float di = dinv[nc];
    uint4 self = hb4[(size_t)nc * 16 + sl];
    float w0 = di * di;
    float acc[8];
    acc[0] = w0 * bflo(self.x); acc[1] = w0 * bfhi(self.x);
    acc[2] = w0 * bflo(self.y); acc[3] = w0 * bfhi(self.y);
    acc[4] = w0 * bflo(self.z); acc[5] = w0 * bfhi(self.z);
    acc[6] = w0 * bflo(self.w); acc[7] = w0 * bfhi(self.w);
    int s0 = row_ptr[nc];
    int deg = ok ? cnt[nc] : 0;
    int2 c0, c1, c2, c3;
    if (deg > 0) {
        int dm = deg - 1;
        c0 = ce[s0];
        c1 = ce[s0 + min(1, dm)];
        c2 = ce[s0 + min(2, dm)];
        c3 = ce[s0 + min(3, dm)];
    }
    for (int i = 0; i < deg; i += 4) {
        int2 p0 = c0, p1 = c1, p2 = c2, p3 = c3;
        int nx = i + 4;
        if (nx < deg) {                      // prefetch next quad
            int dm = deg - 1;
            c0 = ce[s0 + nx];
            c1 = ce[s0 + min(nx + 1, dm)];
            c2 = ce[s0 + min(nx + 2, dm)];
            c3 = ce[s0 + min(nx + 3, dm)];
        }
        uint4 u0 = hb4[(size_t)p0.x * 16 + sl];   // 4 gathers in flight
        uint4 u1 = hb4[(size_t)p1.x * 16 + sl];
        uint4 u2 = hb4[(size_t)p2.x * 16 + sl];
        uint4 u3 = hb4[(size_t)p3.x * 16 + sl];
        float w1 = (i + 1 < deg) ? __int_as_float(p1.y) : 0.f;
        float w2 = (i + 2 < deg) ? __int_as_float(p2.y) : 0.f;
        float w3 = (i + 3 < deg) ? __int_as_float(p3.y) : 0.f;
        fma8(acc, __int_as_float(p0.y), u0);
        fma8(acc, w1, u1);
        fma8(acc, w2, u2);
        fma8(acc, w3, u3);
    }
    if (ok) {
        uint4 o;
        o.x = pack_bf16(acc[0], acc[1]);
        o.y = pack_bf16(acc[2], acc[3]);
        o.z = pack_bf16(acc[4], acc[5]);
        o.w = pack_bf16(acc[6], acc[7]);
        out4[(size_t)node * 16 + sl] = o;
    }
}

// ---------------- MFMA bf16 GEMM (swapped operands): Cb = relu(A @ W + b) --------
// mfma(arg0=Wt-frag, arg1=A-frag): D[i][j] = sum_k Wt[n0+i][k] * A[m0+j][k]
//   = C[m0+j][n0+i].  D layout: lane(quad,lr) reg r -> C[m0+lr][n0+quad*4+r].
// => each lane holds 4 CONSECUTIVE output columns of one row: direct uint2 store.
// Wt staged once per block in LDS (padded); no output LDS, no post-MFMA barriers.

__global__ __launch_bounds__(256) void gemm_mfma(const unsigned short* __restrict__ A,
                                                 const unsigned short* __restrict__ Wt,
                                                 const float* __restrict__ bias,
                                                 unsigned short* __restrict__ Cb) {
    __shared__ unsigned short sm[128 * WPAD];   // 34816 B (Wt only)
    const int t = threadIdx.x;
    const int wave = t >> 6, lane = t & 63;
    const int quad = lane >> 4, lr = lane & 15;
    const size_t row0 = (size_t)blockIdx.x * 128 + wave * 32;

    {   // stage Wt -> sm (row r = t>>1, half h = t&1)
        int r = t >> 1, h = t & 1;
        const uint4* s = (const uint4*)(Wt + r * 128 + h * 64);
        uint4* d = (uint4*)(sm + r * WPAD + h * 64);
#pragma unroll
        for (int i = 0; i < 8; ++i) d[i] = s[i];
    }
    __syncthreads();

    f32x4 acc[2][8];
#pragma unroll
    for (int i2 = 0; i2 < 2; ++i2)
#pragma unroll
        for (int ct = 0; ct < 8; ++ct) acc[i2][ct] = (f32x4){0.f, 0.f, 0.f, 0.f};

    const unsigned short* arow0 = A + (row0 + lr) * 128;
    const unsigned short* arow1 = arow0 + 16 * 128;
#pragma unroll
    for (int kc = 0; kc < 4; ++kc) {
        int kb = kc * 32 + quad * 8;
        bf16x8 a0 = *(const bf16x8*)(arow0 + kb);   // "B"-operand, m-tile 0
        bf16x8 a1 = *(const bf16x8*)(arow1 + kb);   // m-tile 1
#pragma unroll
        for (int ct = 0; ct < 8; ++ct) {
            bf16x8 w = *(const bf16x8*)(sm + (ct * 16 + lr) * WPAD + kb);
            acc[0][ct] = __builtin_amdgcn_mfma_f32_16x16x32_bf16(w, a0, acc[0][ct], 0, 0, 0);
            acc[1][ct] = __builtin_amdgcn_mfma_f32_16x16x32_bf16(w, a1, acc[1][ct], 0, 0, 0);
        }
    }

    // epilogue: bias + relu, pack 4 bf16 (consecutive cols) -> uint2 direct store
#pragma unroll
    for (int i2 = 0; i2 < 2; ++i2) {
        unsigned short* crow = Cb + (row0 + i2 * 16 + lr) * 128;
#pragma unroll
        for (int ct = 0; ct < 8; ++ct) {
            float4 bq = *(const float4*)&bias[ct * 16 + quad * 4];
            float v0 = fmaxf(acc[i2][ct][0] + bq.x, 0.f);
            float v1 = fmaxf(acc[i2][ct][1] + bq.y, 0.f);
            float v2 = fmaxf(acc[i2][ct][2] + bq.z, 0.f);
            float v3 = fmaxf(acc[i2][ct][3] + bq.w, 0.f);
            uint2 p;
            p.x = pack_bf16(v0, v1);
            p.y = pack_bf16(v2, v3);
            *(uint2*)(crow + ct * 16 + quad * 4) = p;
        }
    }
}

// ---------------- pooling: 16 partial blocks per graph, bf16 reads ----------------

__global__ void pool_part(const unsigned short* __restrict__ h,
                          const int* __restrict__ cluster,
                          float* __restrict__ part_sums, int* __restrict__ part_cnts,
                          int npg) {
    int blk = blockIdx.x;
    int g = blk / NPARTS, p = blk % NPARTS;
    int j = threadIdx.x;
    int per = npg / NPARTS;
    int base = g * npg + p * per;
    float a0 = 0.f, a1 = 0.f, a2 = 0.f;
    int n0 = 0, n1 = 0, n2 = 0;
    for (int i = 0; i < per; ++i) {
        int node = base + i;
        float v = bfs(h[(size_t)node * 128 + j]);
        int c = cluster[node];
        if (c == 0)      { a0 += v; n0++; }
        else if (c == 1) { a1 += v; n1++; }
        else             { a2 += v; n2++; }
    }
    size_t o = (size_t)blk * 3 * 128 + j;
    part_sums[o]       = a0;
    part_sums[o + 128] = a1;
    part_sums[o + 256] = a2;
    if (j == 0) {
        part_cnts[blk * 3 + 0] = n0;
        part_cnts[blk * 3 + 1] = n1;
        part_cnts[blk * 3 + 2] = n2;
    }
}

// head over POOLED AGG3 INPUT: z_t = sum_c [n_c>0] ( (s_c[t]/n_c)*wv_c[t]
//                                                  + b3[t]*Wl[c*128+t] )
__global__ void head_kernel(const float* __restrict__ part_sums,
                            const int* __restrict__ part_cnts,
                            const float* __restrict__ wv, const float* __restrict__ b3,
                            const float* __restrict__ Wl, const float* __restrict__ bl,
                            float* __restrict__ out) {
    int b = blockIdx.x, t = threadIdx.x;    // 128 threads
    float s0 = 0.f, s1 = 0.f, s2 = 0.f;
    int n0 = 0, n1 = 0, n2 = 0;
#pragma unroll
    for (int p = 0; p < NPARTS; ++p) {
        int blk = b * NPARTS + p;
        size_t o = (size_t)blk * 3 * 128 + t;
        s0 += part_sums[o];
        s1 += part_sums[o + 128];
        s2 += part_sums[o + 256];
        n0 += part_cnts[blk * 3 + 0];
        n1 += part_cnts[blk * 3 + 1];
        n2 += part_cnts[blk * 3 + 2];
    }
    float bt = b3[t];
    float z = 0.f;
    if (n0 > 0) z += (s0 / (float)n0) * wv[t]       + bt * Wl[t];
    if (n1 > 0) z += (s1 / (float)n1) * wv[128 + t] + bt * Wl[128 + t];
    if (n2 > 0) z += (s2 / (float)n2) * wv[256 + t] + bt * Wl[256 + t];
    for (int off = 32; off > 0; off >>= 1) z += __shfl_down(z, off);
    __shared__ float partial[2];
    if ((t & 63) == 0) partial[t >> 6] = z;
    __syncthreads();
    if (t == 0) {
        float zz = partial[0] + partial[1] + bl[0];
        out[b] = 1.0f / (1.0f + expf(-zz));
    }
}

// ---------------- host ----------------

extern "C" void kernel_launch(void* const* d_in, const int* in_sizes, int n_in,
                              void* d_out, int out_size, void* d_ws, size_t ws_size,
                              hipStream_t stream) {
    const float* x  = (const float*)d_in[0];
    const int*   ei = (const int*)d_in[1];
    const float* W1 = (const float*)d_in[3];
    const float* b1 = (const float*)d_in[4];
    const float* W2 = (const float*)d_in[5];
    const float* b2 = (const float*)d_in[6];
    const float* W3 = (const float*)d_in[7];
    const float* b3 = (const float*)d_in[8];
    const float* Wl = (const float*)d_in[9];
    const float* bl = (const float*)d_in[10];
    float* out = (float*)d_out;

    const int N = in_sizes[0] / 128;        // 100000
    const int E = in_sizes[1] / 2;          // 600000
    const int B = out_size;                 // 250
    const int Npad = (N + 127) & ~127;      // 100096
    const int npg = N / B;                  // 400

    const int* srcp = ei;
    const int* dstp = ei + E;

    char* ws = (char*)d_ws;
    size_t off = 0;
    auto alloc = [&](size_t bytes) -> char* {
        char* p = ws + off;
        off += (bytes + 255) & ~(size_t)255;
        return p;
    };
    unsigned short* hb  = (unsigned short*)alloc((size_t)Npad * 128 * 2); // bf16 h
    unsigned short* ab  = (unsigned short*)alloc((size_t)Npad * 128 * 2); // bf16 agg out
    unsigned short* wt  = (unsigned short*)alloc((size_t)2 * 16384 * 2);  // Wt bf16 x2
    float* wv      = (float*)alloc(384 * 4);                              // W3 @ Wl
    float* dinv    = (float*)alloc((size_t)N * 4);
    int*   row_ptr = (int*)  alloc((size_t)N * 4);
    int*   cluster = (int*)  alloc((size_t)N * 4);
    int2*  ce      = (int2*) alloc((size_t)E * 8);
    int*   bsums   = (int*)  alloc(512 * 4);
    float* psums   = (float*)alloc((size_t)B * NPARTS * 3 * 128 * 4);
    int*   pcnts   = (int*)  alloc((size_t)B * NPARTS * 3 * 4);
    // --- contiguous zero-region: cnt | fill (one memset) ---
    int*   cnt     = (int*)  alloc((size_t)N * 4);
    int*   fill    = (int*)  alloc((size_t)N * 4);
    size_t zspan = (size_t)((char*)fill + (size_t)N * 4 - (char*)cnt);
    (void)ws_size; (void)n_in;

    hipMemsetAsync(cnt, 0, zspan, stream);

    int cb = (E + 255) / 256;               // 2344
    count_wtrans<<<cb + 130, 256, 0, stream>>>(dstp, cnt, E, W1, W2, W3, Wl,
                                               wt, wv, cb);
    prep_kernel<<<(N * 32 + 255) / 256, 256, 0, stream>>>(x, (unsigned*)hb, cnt,
                                                          dinv, cluster, N * 32);

    int scanBlocks = (N + 1023) / 1024;     // 98
    scan_block<<<scanBlocks, 256, 0, stream>>>(cnt, row_ptr, bsums, N);
    scan_add2<<<scanBlocks, 256, 0, stream>>>(row_ptr, bsums, N);

    fill_kernel<<<(E + 255) / 256, 256, 0, stream>>>(srcp, dstp, row_ptr, fill,
                                                     ce, dinv, E);

    int gemmBlocks = Npad / 128;            // 782
    int aggBlocks = (N + 15) / 16;          // 6250

    agg_kernel<<<aggBlocks, 256, 0, stream>>>((const uint4*)hb, (uint4*)ab,
                                              row_ptr, cnt, ce, dinv, N);
    gemm_mfma<<<gemmBlocks, 256, 0, stream>>>(ab, wt,         b1, hb);
    agg_kernel<<<aggBlocks, 256, 0, stream>>>((const uint4*)hb, (uint4*)ab,
                                              row_ptr, cnt, ce, dinv, N);
    gemm_mfma<<<gemmBlocks, 256, 0, stream>>>(ab, wt + 16384, b2, hb);
    agg_kernel<<<aggBlocks, 256, 0, stream>>>((const uint4*)hb, (uint4*)ab,
                                              row_ptr, cnt, ce, dinv, N);

    pool_part<<<B * NPARTS, 128, 0, stream>>>(ab, cluster, psums, pcnts, npg);
    head_kernel<<<B, 128, 0, stream>>>(psums, pcnts, wv, b3, Wl, bl, out);
}

// Round 5
// 304.971 us; speedup vs baseline: 1.5931x; 1.0612x over previous
//
#include <hip/hip_runtime.h>
#include <hip/hip_bf16.h>
#include <math.h>

// N=100000 nodes, E=600000 edges, F=H=128, B=250 graphs, 400 nodes/graph.
//
// Pipeline (bf16 h, fp32 accum):
//   memset(cnt|fill) -> countprep (count + x->bf16/cluster + wtrans + wv)
//   -> scan_block (+dinv) -> scan_add2 -> fill (CSR (col,w) int2)
//   -> agg1 -> gemm1(relu) -> agg2 -> gemm2(relu) -> agg_pool -> head(wv)
//
// R1-R6: 671 -> 337: pool partials, bf16 gathers, MFMA gemm, 4-node/wave agg +
//        edge weights, unroll-4 in-flight gathers, swapped-operand direct-store.
// R7 FAILED (486): agg+gemm fusion collapsed wave count + barrier imbalance.
//        Gather speed = MANY independent waves.
// R8 FAILED (474): pooled gemm epilogue = 102us LDS-atomic 16-way same-address
//        serialization. Contention-free partials win.
// R9  (334): R6 structure + neutral merges.
// R10 (323): layer-3 GEMM eliminated algebraically (wv = W3@Wl; head pools ab).
// R11: (a) pooling commutes with aggregation: agg_pool keeps agg's exact
//        6250-block/4-node-wave shape, accumulates into PER-WAVE private LDS
//        (serialized over 4 lane-groups -> no atomics, no collisions), one
//        barrier, per-block partials (NPARTS=25). Kills ab write + pool_part.
//      (b) dinv moved into scan_block (reads cnt anyway) -> prep loses its
//        count dependency -> merged into countprep (BW work fills atomic
//        latency). 13 -> 11 dispatches.

#define WAVE 64
#define NPARTS 25   // aggpool blocks per graph (16 nodes per block)
#define WPAD 136    // padded LDS row stride (ushorts) for conflict-free ds_read_b128

typedef __attribute__((ext_vector_type(8))) short bf16x8;
typedef __attribute__((ext_vector_type(4))) float f32x4;

__device__ __forceinline__ float bflo(unsigned u) { return __uint_as_float(u << 16); }
__device__ __forceinline__ float bfhi(unsigned u) { return __uint_as_float(u & 0xffff0000u); }
__device__ __forceinline__ float bfs(unsigned short s) {
    return __uint_as_float(((unsigned)s) << 16);
}
__device__ __forceinline__ unsigned short bf16r(float f) {
    unsigned u = __float_as_uint(f);
    return (unsigned short)((u + 0x7fffu + ((u >> 16) & 1u)) >> 16);
}
__device__ __forceinline__ unsigned pack_bf16(float a, float b) {
    return (unsigned)bf16r(a) | ((unsigned)bf16r(b) << 16);
}
__device__ __forceinline__ void fma8(float* acc, float w, uint4 u) {
    acc[0] += w * bflo(u.x); acc[1] += w * bfhi(u.x);
    acc[2] += w * bflo(u.y); acc[3] += w * bfhi(u.y);
    acc[4] += w * bflo(u.z); acc[5] += w * bfhi(u.z);
    acc[6] += w * bflo(u.w); acc[7] += w * bfhi(u.w);
}

// shared gather-accumulate body: acc[8] fp32 for one node (16-lane group view)
__device__ __forceinline__ void agg_node(const uint4* __restrict__ hb4,
                                         const int* __restrict__ row_ptr,
                                         const int* __restrict__ cnt,
                                         const int2* __restrict__ ce,
                                         const float* __restrict__ dinv,
                                         int nc, bool ok, int sl, float* acc) {
    float di = dinv[nc];
    uint4 self = hb4[(size_t)nc * 16 + sl];
    float w0 = di * di;
    acc[0] = w0 * bflo(self.x); acc[1] = w0 * bfhi(self.x);
    acc[2] = w0 * bflo(self.y); acc[3] = w0 * bfhi(self.y);
    acc[4] = w0 * bflo(self.z); acc[5] = w0 * bfhi(self.z);
    acc[6] = w0 * bflo(self.w); acc[7] = w0 * bfhi(self.w);
    int s0 = row_ptr[nc];
    int deg = ok ? cnt[nc] : 0;
    int2 c0, c1, c2, c3;
    if (deg > 0) {
        int dm = deg - 1;
        c0 = ce[s0];
        c1 = ce[s0 + min(1, dm)];
        c2 = ce[s0 + min(2, dm)];
        c3 = ce[s0 + min(3, dm)];
    }
    for (int i = 0; i < deg; i += 4) {
        int2 p0 = c0, p1 = c1, p2 = c2, p3 = c3;
        int nx = i + 4;
        if (nx < deg) {                      // prefetch next quad
            int dm = deg - 1;
            c0 = ce[s0 + nx];
            c1 = ce[s0 + min(nx + 1, dm)];
            c2 = ce[s0 + min(nx + 2, dm)];
            c3 = ce[s0 + min(nx + 3, dm)];
        }
        uint4 u0 = hb4[(size_t)p0.x * 16 + sl];   // 4 gathers in flight
        uint4 u1 = hb4[(size_t)p1.x * 16 + sl];
        uint4 u2 = hb4[(size_t)p2.x * 16 + sl];
        uint4 u3 = hb4[(size_t)p3.x * 16 + sl];
        float w1 = (i + 1 < deg) ? __int_as_float(p1.y) : 0.f;
        float w2 = (i + 2 < deg) ? __int_as_float(p2.y) : 0.f;
        float w3 = (i + 3 < deg) ? __int_as_float(p3.y) : 0.f;
        fma8(acc, __int_as_float(p0.y), u0);
        fma8(acc, w1, u1);
        fma8(acc, w2, u2);
        fma8(acc, w3, u3);
    }
}

// ---------------- prologue mega-kernel ----------------
// blocks [0,cb): degree count; [cb,cb+128): W1,W2 transpose to bf16;
// [cb+128,cb+130): wv = W3@Wl; [cb+130, ...): x->bf16 + cluster

__global__ void countprep(const int* __restrict__ dst, int* __restrict__ cnt, int ne,
                          const float* __restrict__ W1, const float* __restrict__ W2,
                          const float* __restrict__ W3, const float* __restrict__ Wl,
                          unsigned short* __restrict__ Wt, float* __restrict__ wv,
                          const float* __restrict__ x, unsigned* __restrict__ hb,
                          int* __restrict__ cluster, int n32, int cb) {
    int b = blockIdx.x;
    if (b < cb) {
        int e = b * 256 + threadIdx.x;
        if (e < ne) atomicAdd(&cnt[dst[e]], 1);
    } else if (b < cb + 128) {
        int bb = b - cb;                               // 0..127
        int idx = (bb & 63) * 256 + threadIdx.x;       // 0..16383
        int layer = bb >> 6;                           // 0,1
        const float* W = (layer == 0) ? W1 : W2;
        int n = idx >> 7, k = idx & 127;
        Wt[layer * 16384 + n * 128 + k] = bf16r(W[k * 128 + n]);
    } else if (b < cb + 130) {
        int idx = (b - cb - 128) * 256 + threadIdx.x;  // 0..511
        if (idx < 384) {
            int c = idx >> 7, k = idx & 127;
            const float* wlc = Wl + c * 128;
            const float* w3r = W3 + k * 128;
            float s = 0.f;
#pragma unroll 8
            for (int n = 0; n < 128; ++n) s += w3r[n] * wlc[n];
            wv[c * 128 + k] = s;
        }
    } else {
        int i = (b - cb - 130) * 256 + threadIdx.x;    // handles 4 floats of x
        if (i < n32) {
            float4 v = ((const float4*)x)[i];
            hb[i * 2 + 0] = pack_bf16(v.x, v.y);
            hb[i * 2 + 1] = pack_bf16(v.z, v.w);
            if ((i & 31) == 31)                        // floats 124..127 of row
                cluster[i >> 5] = (int)(v.w + 2.0f * v.z + 0.5f);
        }
    }
}

// exclusive scan of cnt -> row_ptr (+ dinv = rsqrt(cnt+1)), 1024 elems per block
__global__ void scan_block(const int* __restrict__ in, int* __restrict__ out,
                           int* __restrict__ bsums, float* __restrict__ dinv, int n) {
    __shared__ int lds[256];
    int t = threadIdx.x;
    int base = blockIdx.x * 1024 + t * 4;
    int v0 = (base + 0 < n) ? in[base + 0] : 0;
    int v1 = (base + 1 < n) ? in[base + 1] : 0;
    int v2 = (base + 2 < n) ? in[base + 2] : 0;
    int v3 = (base + 3 < n) ? in[base + 3] : 0;
    int s = v0 + v1 + v2 + v3;
    lds[t] = s;
    __syncthreads();
    for (int off = 1; off < 256; off <<= 1) {
        int add = (t >= off) ? lds[t - off] : 0;
        __syncthreads();
        lds[t] += add;
        __syncthreads();
    }
    int excl = lds[t] - s;
    if (base + 0 < n) { out[base + 0] = excl;           dinv[base + 0] = rsqrtf((float)(v0 + 1)); }
    if (base + 1 < n) { out[base + 1] = excl + v0;      dinv[base + 1] = rsqrtf((float)(v1 + 1)); }
    if (base + 2 < n) { out[base + 2] = excl + v0 + v1; dinv[base + 2] = rsqrtf((float)(v2 + 1)); }
    if (base + 3 < n) { out[base + 3] = excl + v0 + v1 + v2;
                        dinv[base + 3] = rsqrtf((float)(v3 + 1)); }
    if (t == 255) bsums[blockIdx.x] = lds[255];
}

// merged scan_bsums+scan_add: each block reduces bsums[0..blockIdx) itself
__global__ void scan_add2(int* __restrict__ out, const int* __restrict__ bsums, int n) {
    __shared__ int red[256];
    int t = threadIdx.x;
    red[t] = (t < blockIdx.x) ? bsums[t] : 0;
    __syncthreads();
    for (int off = 128; off > 0; off >>= 1) {
        if (t < off) red[t] += red[t + off];
        __syncthreads();
    }
    int add = red[0];
    int base = blockIdx.x * 1024 + t * 4;
#pragma unroll
    for (int i = 0; i < 4; ++i)
        if (base + i < n) out[base + i] += add;
}

// CSR fill with precomputed edge weight: ce[pos] = (src, dinv[src]*dinv[dst])
__global__ void fill_kernel(const int* __restrict__ src, const int* __restrict__ dst,
                            const int* __restrict__ row_ptr, int* __restrict__ fill,
                            int2* __restrict__ ce, const float* __restrict__ dinv,
                            int ne) {
    int e = blockIdx.x * blockDim.x + threadIdx.x;
    if (e < ne) {
        int d = dst[e], s = src[e];
        int pos = row_ptr[d] + atomicAdd(&fill[d], 1);
        ce[pos] = make_int2(s, __float_as_int(dinv[s] * dinv[d]));
    }
}

// ---------------- aggregation: 4 nodes/wave, unroll-4 pipelined gathers ----------
// out[n][:] = dinv[n]^2 * hb[n][:] + sum_{(s,w) in CSR(n)} w * hb[s][:]

__global__ void agg_kernel(const uint4* __restrict__ hb4, uint4* __restrict__ out4,
                           const int* __restrict__ row_ptr, const int* __restrict__ cnt,
                           const int2* __restrict__ ce, const float* __restrict__ dinv,
                           int n) {
    int wid = blockIdx.x * (blockDim.x >> 6) + (threadIdx.x >> 6);
    int lane = threadIdx.x & 63;
    int g = lane >> 4, sl = lane & 15;     // group (node slot) and sublane
    int node = wid * 4 + g;
    bool ok = node < n;
    int nc = ok ? node : (n - 1);
    float acc[8];
    agg_node(hb4, row_ptr, cnt, ce, dinv, nc, ok, sl, acc);
    if (ok) {
        uint4 o;
        o.x = pack_bf16(acc[0], acc[1]);
        o.y = pack_bf16(acc[2], acc[3]);
        o.z = pack_bf16(acc[4], acc[5]);
        o.w = pack_bf16(acc[6], acc[7]);
        out4[(size_t)node * 16 + sl] = o;
    }
}

// ---------------- agg3 + pooling fused: per-wave private LDS, no atomics --------
// 6250 blocks x 16 nodes (exactly agg's wave shape). Each wave accumulates its
// 4 nodes' fp32 agg rows into its own smW[wave][3][128] (serialized over the
// 4 lane-groups -> disjoint addresses), then one barrier + 4-way tree combine.

__global__ __launch_bounds__(256) void agg_pool(
    const uint4* __restrict__ hb4,
    const int* __restrict__ row_ptr, const int* __restrict__ cnt,
    const int2* __restrict__ ce, const float* __restrict__ dinv,
    const int* __restrict__ cluster,
    float* __restrict__ psums, int* __restrict__ pcnts, int n) {
    __shared__ float smW[4][3][128];
    __shared__ int smC[4][3];
    const int t = threadIdx.x;
    for (int i = t; i < 4 * 3 * 128; i += 256) ((float*)smW)[i] = 0.f;
    if (t < 12) ((int*)smC)[t] = 0;
    __syncthreads();

    const int wave = t >> 6, lane = t & 63;
    const int g = lane >> 4, sl = lane & 15;
    const int node = blockIdx.x * 16 + wave * 4 + g;
    const bool ok = node < n;
    const int nc = ok ? node : (n - 1);
    float acc[8];
    agg_node(hb4, row_ptr, cnt, ce, dinv, nc, ok, sl, acc);

    const int cl = ok ? cluster[nc] : 0;
    // serialize the 4 lane-groups of this wave (same cluster -> same addresses)
#pragma unroll
    for (int g2 = 0; g2 < 4; ++g2) {
        if (g == g2 && ok) {
            float* dstp = &smW[wave][cl][sl * 8];
#pragma unroll
            for (int j = 0; j < 8; ++j) dstp[j] += acc[j];
            if (sl == 0) smC[wave][cl] += 1;
        }
    }
    __syncthreads();

    if (t < 128) {
#pragma unroll
        for (int c = 0; c < 3; ++c) {
            float s = smW[0][c][t] + smW[1][c][t] + smW[2][c][t] + smW[3][c][t];
            psums[((size_t)blockIdx.x * 3 + c) * 128 + t] = s;
        }
    }
    if (t < 3)
        pcnts[blockIdx.x * 3 + t] = smC[0][t] + smC[1][t] + smC[2][t] + smC[3][t];
}

// ---------------- MFMA bf16 GEMM (swapped operands): Cb = relu(A @ W + b) --------
// mfma(arg0=Wt-frag, arg1=A-frag): D[i][j] = sum_k Wt[n0+i][k] * A[m0+j][k]
//   = C[m0+j][n0+i].  D layout: lane(quad,lr) reg r -> C[m0+lr][n0+quad*4+r].
// => each lane holds 4 CONSECUTIVE output columns of one row: direct uint2 store.
// Wt staged once per block in LDS (padded); no output LDS, no post-MFMA barriers.

__global__ __launch_bounds__(256) void gemm_mfma(const unsigned short* __restrict__ A,
                                                 const unsigned short* __restrict__ Wt,
                                                 const float* __restrict__ bias,
                                                 unsigned short* __restrict__ Cb) {
    __shared__ unsigned short sm[128 * WPAD];   // 34816 B (Wt only)
    const int t = threadIdx.x;
    const int wave = t >> 6, lane = t & 63;
    const int quad = lane >> 4, lr = lane & 15;
    const size_t row0 = (size_t)blockIdx.x * 128 + wave * 32;

    {   // stage Wt -> sm (row r = t>>1, half h = t&1)
        int r = t >> 1, h = t & 1;
        const uint4* s = (const uint4*)(Wt + r * 128 + h * 64);
        uint4* d = (uint4*)(sm + r * WPAD + h * 64);
#pragma unroll
        for (int i = 0; i < 8; ++i) d[i] = s[i];
    }
    __syncthreads();

    f32x4 acc[2][8];
#pragma unroll
    for (int i2 = 0; i2 < 2; ++i2)
#pragma unroll
        for (int ct = 0; ct < 8; ++ct) acc[i2][ct] = (f32x4){0.f, 0.f, 0.f, 0.f};

    const unsigned short* arow0 = A + (row0 + lr) * 128;
    const unsigned short* arow1 = arow0 + 16 * 128;
#pragma unroll
    for (int kc = 0; kc < 4; ++kc) {
        int kb = kc * 32 + quad * 8;
        bf16x8 a0 = *(const bf16x8*)(arow0 + kb);   // "B"-operand, m-tile 0
        bf16x8 a1 = *(const bf16x8*)(arow1 + kb);   // m-tile 1
#pragma unroll
        for (int ct = 0; ct < 8; ++ct) {
            bf16x8 w = *(const bf16x8*)(sm + (ct * 16 + lr) * WPAD + kb);
            acc[0][ct] = __builtin_amdgcn_mfma_f32_16x16x32_bf16(w, a0, acc[0][ct], 0, 0, 0);
            acc[1][ct] = __builtin_amdgcn_mfma_f32_16x16x32_bf16(w, a1, acc[1][ct], 0, 0, 0);
        }
    }

    // epilogue: bias + relu, pack 4 bf16 (consecutive cols) -> uint2 direct store
#pragma unroll
    for (int i2 = 0; i2 < 2; ++i2) {
        unsigned short* crow = Cb + (row0 + i2 * 16 + lr) * 128;
#pragma unroll
        for (int ct = 0; ct < 8; ++ct) {
            float4 bq = *(const float4*)&bias[ct * 16 + quad * 4];
            float v0 = fmaxf(acc[i2][ct][0] + bq.x, 0.f);
            float v1 = fmaxf(acc[i2][ct][1] + bq.y, 0.f);
            float v2 = fmaxf(acc[i2][ct][2] + bq.z, 0.f);
            float v3 = fmaxf(acc[i2][ct][3] + bq.w, 0.f);
            uint2 p;
            p.x = pack_bf16(v0, v1);
            p.y = pack_bf16(v2, v3);
            *(uint2*)(crow + ct * 16 + quad * 4) = p;
        }
    }
}

// head: z_t = sum_c [n_c>0] ( (s_c[t]/n_c)*wv_c[t] + b3[t]*Wl[c*128+t] )
__global__ void head_kernel(const float* __restrict__ part_sums,
                            const int* __restrict__ part_cnts,
                            const float* __restrict__ wv, const float* __restrict__ b3,
                            const float* __restrict__ Wl, const float* __restrict__ bl,
                            float* __restrict__ out) {
    int b = blockIdx.x, t = threadIdx.x;    // 128 threads
    float s0 = 0.f, s1 = 0.f, s2 = 0.f;
    int n0 = 0, n1 = 0, n2 = 0;
#pragma unroll
    for (int p = 0; p < NPARTS; ++p) {
        int blk = b * NPARTS + p;
        size_t o = (size_t)blk * 384 + t;
        s0 += part_sums[o];
        s1 += part_sums[o + 128];
        s2 += part_sums[o + 256];
        n0 += part_cnts[blk * 3 + 0];
        n1 += part_cnts[blk * 3 + 1];
        n2 += part_cnts[blk * 3 + 2];
    }
    float bt = b3[t];
    float z = 0.f;
    if (n0 > 0) z += (s0 / (float)n0) * wv[t]       + bt * Wl[t];
    if (n1 > 0) z += (s1 / (float)n1) * wv[128 + t] + bt * Wl[128 + t];
    if (n2 > 0) z += (s2 / (float)n2) * wv[256 + t] + bt * Wl[256 + t];
    for (int off = 32; off > 0; off >>= 1) z += __shfl_down(z, off);
    __shared__ float partial[2];
    if ((t & 63) == 0) partial[t >> 6] = z;
    __syncthreads();
    if (t == 0) {
        float zz = partial[0] + partial[1] + bl[0];
        out[b] = 1.0f / (1.0f + expf(-zz));
    }
}

// ---------------- host ----------------

extern "C" void kernel_launch(void* const* d_in, const int* in_sizes, int n_in,
                              void* d_out, int out_size, void* d_ws, size_t ws_size,
                              hipStream_t stream) {
    const float* x  = (const float*)d_in[0];
    const int*   ei = (const int*)d_in[1];
    const float* W1 = (const float*)d_in[3];
    const float* b1 = (const float*)d_in[4];
    const float* W2 = (const float*)d_in[5];
    const float* b2 = (const float*)d_in[6];
    const float* W3 = (const float*)d_in[7];
    const float* b3 = (const float*)d_in[8];
    const float* Wl = (const float*)d_in[9];
    const float* bl = (const float*)d_in[10];
    float* out = (float*)d_out;

    const int N = in_sizes[0] / 128;        // 100000
    const int E = in_sizes[1] / 2;          // 600000
    const int B = out_size;                 // 250
    const int Npad = (N + 127) & ~127;      // 100096
    const int npg = N / B;                  // 400
    (void)npg;

    const int* srcp = ei;
    const int* dstp = ei + E;

    char* ws = (char*)d_ws;
    size_t off = 0;
    auto alloc = [&](size_t bytes) -> char* {
        char* p = ws + off;
        off += (bytes + 255) & ~(size_t)255;
        return p;
    };
    unsigned short* hb  = (unsigned short*)alloc((size_t)Npad * 128 * 2); // bf16 h
    unsigned short* ab  = (unsigned short*)alloc((size_t)Npad * 128 * 2); // bf16 agg out
    unsigned short* wt  = (unsigned short*)alloc((size_t)2 * 16384 * 2);  // Wt bf16 x2
    float* wv      = (float*)alloc(384 * 4);                              // W3 @ Wl
    float* dinv    = (float*)alloc((size_t)N * 4);
    int*   row_ptr = (int*)  alloc((size_t)N * 4);
    int*   cluster = (int*)  alloc((size_t)N * 4);
    int2*  ce      = (int2*) alloc((size_t)E * 8);
    int*   bsums   = (int*)  alloc(512 * 4);
    float* psums   = (float*)alloc((size_t)B * NPARTS * 3 * 128 * 4);
    int*   pcnts   = (int*)  alloc((size_t)B * NPARTS * 3 * 4);
    // --- contiguous zero-region: cnt | fill (one memset) ---
    int*   cnt     = (int*)  alloc((size_t)N * 4);
    int*   fill    = (int*)  alloc((size_t)N * 4);
    size_t zspan = (size_t)((char*)fill + (size_t)N * 4 - (char*)cnt);
    (void)ws_size; (void)n_in;

    hipMemsetAsync(cnt, 0, zspan, stream);

    int cb = (E + 255) / 256;               // 2344
    int prepBlocks = (N * 32 + 255) / 256;  // 12500
    countprep<<<cb + 130 + prepBlocks, 256, 0, stream>>>(
        dstp, cnt, E, W1, W2, W3, Wl, wt, wv, x, (unsigned*)hb, cluster,
        N * 32, cb);

    int scanBlocks = (N + 1023) / 1024;     // 98
    scan_block<<<scanBlocks, 256, 0, stream>>>(cnt, row_ptr, bsums, dinv, N);
    scan_add2<<<scanBlocks, 256, 0, stream>>>(row_ptr, bsums, N);

    fill_kernel<<<(E + 255) / 256, 256, 0, stream>>>(srcp, dstp, row_ptr, fill,
                                                     ce, dinv, E);

    int gemmBlocks = Npad / 128;            // 782
    int aggBlocks = (N + 15) / 16;          // 6250

    agg_kernel<<<aggBlocks, 256, 0, stream>>>((const uint4*)hb, (uint4*)ab,
                                              row_ptr, cnt, ce, dinv, N);
    gemm_mfma<<<gemmBlocks, 256, 0, stream>>>(ab, wt,         b1, hb);
    agg_kernel<<<aggBlocks, 256, 0, stream>>>((const uint4*)hb, (uint4*)ab,
                                              row_ptr, cnt, ce, dinv, N);
    gemm_mfma<<<gemmBlocks, 256, 0, stream>>>(ab, wt + 16384, b2, hb);

    agg_pool<<<aggBlocks, 256, 0, stream>>>((const uint4*)hb, row_ptr, cnt, ce,
                                            dinv, cluster, psums, pcnts, N);
    head_kernel<<<B, 128, 0, stream>>>(psums, pcnts, wv, b3, Wl, bl, out);
}